// Round 9
// baseline (333.214 us; speedup 1.0000x reference)
//
#include <hip/hip_runtime.h>
#include <hip/hip_bf16.h>

#define LEAKC 0.1f

__device__ __forceinline__ float lrelu(float v){ return v > 0.f ? v : LEAKC*v; }
__device__ __forceinline__ ushort f2b(float f){
  __hip_bfloat16 h = __float2bfloat16(f);
  return *reinterpret_cast<ushort*>(&h);
}

typedef __attribute__((ext_vector_type(8))) short bf16x8;
typedef __attribute__((ext_vector_type(4))) float f32x4;

// ---------------- styles ----------------
__global__ void style_kernel(const float* __restrict__ g,
                             const float* __restrict__ sp1,
                             const float* __restrict__ sp2,
                             float* __restrict__ s1, float* __restrict__ s2){
  int t = threadIdx.x;
  if (t < 64){
    int b = t >> 5, j = t & 31;
    float a = 0.f;
    for (int k=0;k<256;k++) a += g[b*256+k]*sp1[j*256+k];
    s1[t] = a;
  } else if (t < 192){
    int u = t - 64;
    int b = u >> 6, j = u & 63;
    float a = 0.f;
    for (int k=0;k<256;k++) a += g[b*256+k]*sp2[j*256+k];
    s2[u] = a;
  }
}

// ---------------- cls + counting sort by class ----------------
__global__ void cls_sort_kernel(const float* __restrict__ label,
                                int* __restrict__ clsb,
                                int* __restrict__ cnt,
                                int* __restrict__ off,
                                int* __restrict__ order){
  __shared__ int h[80], hoff[80];
  int tid = threadIdx.x;             // 256, n = b*128 + t
  if (tid < 80) h[tid] = 0;
  __syncthreads();
  int b = tid >> 7, t = tid & 127;
  const float* p = label + (t*2 + b)*80;
  float best = p[0]; int bi = 0;
  for (int c=1;c<80;c++){ float v = p[c]; if (v > best){ best = v; bi = c; } }
  clsb[tid] = bi;
  atomicAdd(&h[bi], 1);
  __syncthreads();
  if (tid == 0){
    int s = 0;
    for (int e=0;e<80;e++){ hoff[e] = s; s += h[e]; }
  }
  __syncthreads();
  if (tid < 80){ cnt[tid] = h[tid]; off[tid] = hoff[tid]; }
  __syncthreads();
  int rank = atomicAdd(&hoff[bi], 1);
  order[rank] = tid;
}

// ---------------- input conv 7x7 -> bf16 out ----------------
__global__ void conv_in_kernel(const float* __restrict__ x,
                               const float* __restrict__ wgt,
                               const float* __restrict__ bias,
                               ushort* __restrict__ out){
  int hw = blockIdx.x*256 + threadIdx.x;
  int y = hw >> 9, w = hw & 511;
  int b = blockIdx.z;
  int o0 = blockIdx.y * 8;
  float acc[8];
  #pragma unroll
  for (int i=0;i<8;i++) acc[i] = bias[o0+i];
  for (int kh=0;kh<7;kh++){
    const float* ip = x + (b*64 + y + kh)*512;
    #pragma unroll
    for (int kw=0;kw<7;kw++){
      int wi = w + kw - 3;
      float v = (wi>=0 && wi<512) ? ip[wi] : 0.f;
      #pragma unroll
      for (int i=0;i<8;i++) acc[i] += v * wgt[(o0+i)*49 + kh*7 + kw];
    }
  }
  #pragma unroll
  for (int i=0;i<8;i++)
    out[((b*64 + o0+i)*58 + y)*512 + w] = f2b(lrelu(acc[i]));
}

// ---------------- weight repack: wb[n][(kh*3+kw)*CM + c] = bf16(w[n][c][kh][kw]) ----------------
template<int CM,int CTOT,int COUT>
__global__ void repack_kernel(const float* __restrict__ w, ushort* __restrict__ wb){
  int i = blockIdx.x*256 + threadIdx.x;
  if (i >= COUT*9*CM) return;
  int c = i % CM; int r = i / CM; int t = r % 9; int n = r / 9;
  wb[i] = f2b(w[((size_t)n*CTOT + c)*9 + t]);
}

// ---------------- MFMA conv: 3x3, pad(0,1), BM=64 (one w-strip), BN=64, K=CM*9 ----------------
template<int CM,int WID,int HIN,int COUT,int MODE,int OUTBF>
__global__ __launch_bounds__(256) void conv_mfma(
    const ushort* __restrict__ in,   // bf16 (2,CM,HIN,WID)
    const ushort* __restrict__ Wb,   // bf16 (COUT, CM*9)
    const float*  __restrict__ mb,   // map (2,COUT,3) or bias (COUT)
    float* __restrict__ outf,
    ushort* __restrict__ outh){
  constexpr int HOUT = HIN - 2;
  constexpr int KTOT = CM*9;
  constexpr int SLABS = CM/32;
  constexpr int NST = 3*SLABS;
  __shared__ ushort A[2][66][40];
  int tid = threadIdx.x, lane = tid & 63, wave = tid >> 6;
  int mt = blockIdx.x;
  int y  = mt / (WID/64), w0 = (mt % (WID/64))*64;
  int n0 = blockIdx.y*64;
  int b  = blockIdx.z;

  f32x4 acc[4];
  #pragma unroll
  for (int nf=0;nf<4;nf++) acc[nf] = (f32x4){0.f,0.f,0.f,0.f};

  auto stage = [&](int s, int bufi){
    int kh = s / SLABS;
    int c0 = (s % SLABS)*32;
    const ushort* base = in + ((size_t)(b*CM + c0)*HIN + (y+kh))*WID;
    int c2 = (tid & 15)*2, m0v = (tid >> 4)*2*2;
    const ushort* p0 = base + (size_t)c2*HIN*WID + w0 + m0v;
    const ushort* p1 = p0 + (size_t)HIN*WID;
    ushort4 va = *(const ushort4*)p0;
    ushort4 vb = *(const ushort4*)p1;
    uint* dst = (uint*)&A[bufi][1+m0v][c2];
    dst[0]  = (uint)va.x | ((uint)vb.x << 16);
    dst[20] = (uint)va.y | ((uint)vb.y << 16);
    dst[40] = (uint)va.z | ((uint)vb.z << 16);
    dst[60] = (uint)va.w | ((uint)vb.w << 16);
    if (tid < 64){
      int c = tid & 31, side = tid >> 5;
      int w = side ? (w0 + 64) : (w0 - 1);
      ushort v = 0;
      if (w >= 0 && w < WID) v = base[(size_t)c*HIN*WID + w];
      A[bufi][side ? 65 : 0][c] = v;
    }
  };

  stage(0, 0);
  __syncthreads();
  for (int s = 0; s < NST; ++s){
    int cur = s & 1;
    if (s + 1 < NST) stage(s+1, cur ^ 1);
    int kh = s / SLABS;
    int c0 = (s % SLABS)*32;
    #pragma unroll
    for (int kw = 0; kw < 3; ++kw){
      bf16x8 a = *(bf16x8*)&A[cur][wave*16 + (lane & 15) + kw][(lane >> 4)*8];
      #pragma unroll
      for (int nf = 0; nf < 4; ++nf){
        const ushort* wp = Wb + (size_t)(n0 + nf*16 + (lane & 15))*KTOT
                              + (kh*3 + kw)*CM + c0 + (lane >> 4)*8;
        bf16x8 bb = *(const bf16x8*)wp;
        acc[nf] = __builtin_amdgcn_mfma_f32_16x16x32_bf16(a, bb, acc[nf], 0, 0, 0);
      }
    }
    __syncthreads();
  }

  int mrow = wave*16 + ((lane >> 4) << 2);
  int w = w0 + mrow;
  #pragma unroll
  for (int nf = 0; nf < 4; ++nf){
    int n = n0 + nf*16 + (lane & 15);
    float r0 = acc[nf][0], r1 = acc[nf][1], r2 = acc[nf][2], r3 = acc[nf][3];
    if (MODE == 0){
      float bb = mb[n];
      r0 += bb; r1 += bb; r2 += bb; r3 += bb;
    } else {
      const float* m3 = mb + (size_t)(b*COUT + n)*3;
      float mL = m3[0], mM = m3[1], mR = m3[2];
      r0 += (w == 0) ? mL : ((w   == WID-1) ? mR : mM);
      r1 += (w+1 == WID-1) ? mR : mM;
      r2 += (w+2 == WID-1) ? mR : mM;
      r3 += (w+3 == WID-1) ? mR : mM;
    }
    r0 = lrelu(r0); r1 = lrelu(r1); r2 = lrelu(r2); r3 = lrelu(r3);
    size_t off = ((size_t)(b*COUT + n)*HOUT + y)*WID + w;
    if (OUTBF){
      ushort4 o = make_ushort4(f2b(r0), f2b(r1), f2b(r2), f2b(r3));
      *(ushort4*)(outh + off) = o;
    } else {
      *(float4*)(outf + off) = make_float4(r0, r1, r2, r3);
    }
  }
}

// ---------------- f32 3x3 conv (small layers), K-split partials ----------------
template<int CM,int CTOT,int HIN,int WID,int COUT,int OPT,int SPLIT>
__global__ void conv3_main1(const float* __restrict__ in,
                            const float* __restrict__ wgt,
                            float* __restrict__ part){
  constexpr int HOUT = HIN - 2;
  constexpr int CSPLIT = CM / SPLIT;
  constexpr int N = 2*COUT*HOUT*WID;
  int hw0 = blockIdx.x*256 + threadIdx.x;
  if (hw0 >= HOUT*WID) return;
  int y = hw0 / WID, w0 = hw0 % WID;
  int b = blockIdx.z;
  int split = blockIdx.y % SPLIT;
  int o0 = (blockIdx.y / SPLIT) * OPT;

  float acc[OPT];
  #pragma unroll
  for (int i=0;i<OPT;i++) acc[i] = 0.f;

  const bool lok = (w0 > 0), rok = (w0 + 1) < WID;
  int c0 = split * CSPLIT;
  for (int c=c0; c<c0+CSPLIT; c++){
    const float* rp = in + ((size_t)(b*CM + c)*HIN + y)*WID + w0;
    #pragma unroll
    for (int kh=0;kh<3;kh++){
      float v0 = lok ? rp[kh*WID - 1] : 0.f;
      float v1 = rp[kh*WID];
      float v2 = rok ? rp[kh*WID + 1] : 0.f;
      #pragma unroll
      for (int i=0;i<OPT;i++){
        const float* wq = wgt + ((size_t)(o0+i)*CTOT + c)*9 + kh*3;
        acc[i] += v0*wq[0] + v1*wq[1] + v2*wq[2];
      }
    }
  }
  #pragma unroll
  for (int i=0;i<OPT;i++)
    part[(size_t)split*N + ((size_t)(b*COUT + o0+i)*HOUT + y)*WID + w0] = acc[i];
}

// ---------------- combine partials + map + lrelu ----------------
template<int SPLIT,int MODE,int COUT,int HOUT,int WID>
__global__ __launch_bounds__(256) void combine_kernel(float* __restrict__ part,
                                                      const float* __restrict__ mapv,
                                                      const float* __restrict__ bias){
  constexpr int N = 2*COUT*HOUT*WID;
  int idx = (blockIdx.x*256 + threadIdx.x)*4;
  if (idx >= N) return;
  float4 v = *(float4*)(part + idx);
  #pragma unroll
  for (int s=1;s<SPLIT;s++){
    float4 u = *(const float4*)(part + (size_t)s*N + idx);
    v.x += u.x; v.y += u.y; v.z += u.z; v.w += u.w;
  }
  int w = idx % WID;
  int r = idx / WID;
  int bo = r / HOUT;
  int o = bo % COUT, b = bo / COUT;
  float* av = (float*)&v;
  if (MODE == 0){
    float bb = bias[o];
    #pragma unroll
    for (int j=0;j<4;j++) av[j] += bb;
  } else if (MODE == 1){
    const float* m = mapv + (size_t)(b*COUT + o)*3;
    #pragma unroll
    for (int j=0;j<4;j++){
      int wj = w + j;
      av[j] += (wj == 0) ? m[0] : ((wj == WID-1) ? m[2] : m[1]);
    }
  } else {
    const float* m = mapv + ((size_t)(b*COUT + o))*WID + w;
    #pragma unroll
    for (int j=0;j<4;j++) av[j] += m[j];
  }
  #pragma unroll
  for (int j=0;j<4;j++) av[j] = lrelu(av[j]);
  *(float4*)(part + idx) = v;
}

// ---------------- 3-value style map ----------------
template<int CS,int CTOT,int COUT,int COFF>
__global__ void map3_kernel(const float* __restrict__ style,
                            const float* __restrict__ wgt,
                            const float* __restrict__ bias,
                            float* __restrict__ mapv){
  int t = threadIdx.x;
  if (t >= 2*COUT) return;
  int b = t / COUT, o = t % COUT;
  float S0=0.f, S1=0.f, S2=0.f;
  for (int c=0;c<CS;c++){
    float s = style[b*CS + c];
    const float* wq = wgt + ((size_t)o*CTOT + COFF + c)*9;
    S0 += s*(wq[0]+wq[3]+wq[6]);
    S1 += s*(wq[1]+wq[4]+wq[7]);
    S2 += s*(wq[2]+wq[5]+wq[8]);
  }
  float bb = bias[o];
  mapv[t*3+0] = S1+S2+bb;
  mapv[t*3+1] = S0+S1+S2+bb;
  mapv[t*3+2] = S0+S1+bb;
}

// ---------------- A6 column map ----------------
__global__ void map6_kernel(const float* __restrict__ spaced,
                            const float* __restrict__ label,
                            const float* __restrict__ wgt,
                            const float* __restrict__ bias,
                            float* __restrict__ mapv){
  int n = blockIdx.x*256 + threadIdx.x;
  int w = n & 127, o = (n >> 7) & 127, b = n >> 14;
  float a = bias[o];
  #pragma unroll
  for (int t=0;t<3;t++){
    int j = w + t - 1;
    if (j < 0 || j >= 128) continue;
    const float* sp = spaced + (j*2 + b)*32;
    const float* lb = label + (j*2 + b)*80;
    for (int c=0;c<32;c++){
      const float* wq = wgt + ((size_t)o*240 + 128 + c)*9 + t;
      a += sp[c]*(wq[0]+wq[3]+wq[6]);
    }
    for (int c=0;c<80;c++){
      const float* wq = wgt + ((size_t)o*240 + 160 + c)*9 + t;
      a += lb[c]*(wq[0]+wq[3]+wq[6]);
    }
  }
  mapv[n] = a;
}

// ---------------- 2x2 mean pool (f32 -> f32) ----------------
__global__ void pool2_kernel(const float* __restrict__ in, float* __restrict__ out,
                             int H, int W, int total){
  int n = blockIdx.x*256 + threadIdx.x;
  if (n >= total) return;
  int Wo = W >> 1;
  int wo = n % Wo;
  int r = n / Wo;
  int Ho = H >> 1;
  int ho = r % Ho;
  int bc = r / Ho;
  const float* p = in + (bc*H + 2*ho)*W + 2*wo;
  out[n] = 0.25f*(p[0] + p[1] + p[W] + p[W+1]);
}

// ---------------- 2x2 mean pool (f32 -> bf16) ----------------
__global__ void pool2_bf16_kernel(const float* __restrict__ in, ushort* __restrict__ out,
                                  int H, int W, int total){
  int n = blockIdx.x*256 + threadIdx.x;
  if (n >= total) return;
  int Wo = W >> 1;
  int wo = n % Wo;
  int r = n / Wo;
  int Ho = H >> 1;
  int ho = r % Ho;
  int bc = r / Ho;
  const float* p = in + (bc*H + 2*ho)*W + 2*wo;
  out[n] = f2b(0.25f*(p[0] + p[1] + p[W] + p[W+1]));
}

// ---------------- pM ----------------
__global__ __launch_bounds__(256) void fm_kernel(const float* __restrict__ A7,
                          const float* __restrict__ fw,
                          const float* __restrict__ fb,
                          float* __restrict__ out){
  __shared__ float red[4];
  int n = blockIdx.x;
  int b = n >> 6, w = n & 63;
  int c = threadIdx.x;
  float a = 0.f;
  #pragma unroll
  for (int r=0;r<3;r++){
    const float* ip = A7 + ((b*256+c)*3+r)*64;
    const float* wp = fw + (c*3+r)*3;
    #pragma unroll
    for (int kw=0;kw<3;kw++){
      int wi = w + kw - 1;
      if (wi>=0 && wi<64) a += ip[wi]*wp[kw];
    }
  }
  #pragma unroll
  for (int off=32; off>0; off>>=1) a += __shfl_down(a, off, 64);
  if ((threadIdx.x & 63) == 0) red[threadIdx.x>>6] = a;
  __syncthreads();
  if (threadIdx.x == 0) out[n] = red[0]+red[1]+red[2]+red[3] + fb[0];
}

// ---------------- im2col: pwg[n][j][d] (d = c*9 + r*3 + kw) ----------------
__global__ void im2col_kernel(const float* __restrict__ A7, float* __restrict__ pwg){
  int i = blockIdx.x*256 + threadIdx.x;   // 256*3*2304 = 1,769,472
  if (i >= 256*3*2304) return;
  int d = i % 2304; int rj = i / 2304; int j = rj % 3; int n = rj / 3;
  int b = n >> 7, t = n & 127; int idx = t >> 1;
  int c = d / 9, rem = d - c*9, r = rem / 3, kw = rem - r*3;
  int col = idx - 2 + kw + j;
  pwg[i] = (col >= 0 && col < 64) ? A7[((size_t)(b*256 + c)*3 + r)*64 + col] : 0.f;
}

// ---------------- cd conv v3: class-grouped, weights read ONCE per (e,o) ----------------
// grid (80, 16): block = class e, 8 outputs (wave owns 2, weights in 72 VGPRs).
// Loop over samples of class e: stage pw from pwg (float4 copy), dot, shfl-reduce.
__global__ __launch_bounds__(256) void cd_conv_kernel(
    const float* __restrict__ pwg,    // (256,3,2304)
    const int*   __restrict__ cnt,    // (80)
    const int*   __restrict__ offv,   // (80)
    const int*   __restrict__ order,  // (256)
    const float* __restrict__ Wc,     // (80,128,2304)
    const float* __restrict__ bcv,    // (80,128)
    float* __restrict__ featg)        // (256,128)
{
  __shared__ float pw[3][2304];
  int e = blockIdx.x, og = blockIdx.y;
  int m = cnt[e];
  if (m == 0) return;
  int base = offv[e];
  int tid = threadIdx.x, lane = tid & 63, wave = tid >> 6;
  int out0 = og*8 + wave*2;

  float4 wr[2][9];
  #pragma unroll
  for (int oi=0;oi<2;oi++){
    const float4* wp = (const float4*)(Wc + ((size_t)e*128 + out0 + oi)*2304);
    #pragma unroll
    for (int k=0;k<9;k++) wr[oi][k] = wp[k*64 + lane];
  }
  float b0 = bcv[e*128 + out0], b1v = bcv[e*128 + out0 + 1];

  for (int s = 0; s < m; ++s){
    int n = order[base + s];
    const float4* src = (const float4*)(pwg + (size_t)n*3*2304);
    float4* dst = (float4*)pw;
    for (int i = tid; i < 1728; i += 256) dst[i] = src[i];
    __syncthreads();

    float a[2][3] = {{0.f,0.f,0.f},{0.f,0.f,0.f}};
    #pragma unroll
    for (int k = 0; k < 9; ++k){
      int d0 = (k*64 + lane)*4;
      float4 p0 = *(const float4*)&pw[0][d0];
      float4 p1 = *(const float4*)&pw[1][d0];
      float4 p2 = *(const float4*)&pw[2][d0];
      #pragma unroll
      for (int oi = 0; oi < 2; ++oi){
        float4 w4 = wr[oi][k];
        a[oi][0] += w4.x*p0.x + w4.y*p0.y + w4.z*p0.z + w4.w*p0.w;
        a[oi][1] += w4.x*p1.x + w4.y*p1.y + w4.z*p1.z + w4.w*p1.w;
        a[oi][2] += w4.x*p2.x + w4.y*p2.y + w4.z*p2.z + w4.w*p2.w;
      }
    }
    #pragma unroll
    for (int off = 32; off > 0; off >>= 1){
      #pragma unroll
      for (int oi = 0; oi < 2; ++oi){
        a[oi][0] += __shfl_down(a[oi][0], off, 64);
        a[oi][1] += __shfl_down(a[oi][1], off, 64);
        a[oi][2] += __shfl_down(a[oi][2], off, 64);
      }
    }
    if (lane == 0){
      featg[(size_t)n*128 + out0] =
        (lrelu(a[0][0]+b0) + lrelu(a[0][1]+b0) + lrelu(a[0][2]+b0)) * (1.f/3.f);
      featg[(size_t)n*128 + out0 + 1] =
        (lrelu(a[1][0]+b1v) + lrelu(a[1][1]+b1v) + lrelu(a[1][2]+b1v)) * (1.f/3.f);
    }
    __syncthreads();
  }
}

// ---------------- cd tail: feat -> fc1 -> fc2 ----------------
__global__ __launch_bounds__(128) void cd_tail_kernel(
    const float* __restrict__ featg,  // (256,128)
    const int*   __restrict__ clsb,
    const float* __restrict__ cstyle, // (2,80,32)
    const float* __restrict__ W1,     // (80,160,128)
    const float* __restrict__ b1,     // (80,128)
    const float* __restrict__ W2,     // (80,128,1)
    const float* __restrict__ b2,     // (80,1)
    float* __restrict__ pChar)        // (256)
{
  __shared__ float feat[160];
  __shared__ float red2[2];
  int n = blockIdx.x, tid = threadIdx.x;
  int b = n >> 7;
  int e = clsb[n];
  int o = tid;
  feat[o] = featg[(size_t)n*128 + o];
  if (tid < 32) feat[128+tid] = cstyle[(b*80 + e)*32 + tid];
  __syncthreads();

  float s = b1[e*128 + o];
  for (int d=0;d<160;d++) s += feat[d]*W1[(e*160 + d)*128 + o];
  float h = s > 0.f ? s : 0.f;
  float contrib = h * W2[e*128 + o];
  #pragma unroll
  for (int off=32; off>0; off>>=1) contrib += __shfl_down(contrib, off, 64);
  if ((tid & 63) == 0) red2[tid>>6] = contrib;
  __syncthreads();
  if (tid == 0) pChar[n] = red2[0] + red2[1] + b2[e];
}

extern "C" void kernel_launch(void* const* d_in, const int* in_sizes, int n_in,
                              void* d_out, int out_size, void* d_ws, size_t ws_size,
                              hipStream_t stream){
  (void)in_sizes; (void)n_in; (void)out_size; (void)ws_size;
  const float* x      = (const float*)d_in[0];
  const float* label  = (const float*)d_in[1];
  const float* g_style= (const float*)d_in[2];
  const float* spaced = (const float*)d_in[3];
  const float* cstyle = (const float*)d_in[4];
  const float* sp1    = (const float*)d_in[5];
  const float* sp2    = (const float*)d_in[6];
  const float* in_w   = (const float*)d_in[7];
  const float* in_b   = (const float*)d_in[8];
  const float* c1w1   = (const float*)d_in[9];
  const float* c1b1   = (const float*)d_in[10];
  const float* c1w2   = (const float*)d_in[11];
  const float* c1b2   = (const float*)d_in[12];
  const float* c2w    = (const float*)d_in[13];
  const float* c2b    = (const float*)d_in[14];
  const float* c3w1   = (const float*)d_in[15];
  const float* c3b1   = (const float*)d_in[16];
  const float* c3w2   = (const float*)d_in[17];
  const float* c3b2   = (const float*)d_in[18];
  const float* fm_w   = (const float*)d_in[19];
  const float* fm_b   = (const float*)d_in[20];
  const float* cdw    = (const float*)d_in[21];
  const float* cdb    = (const float*)d_in[22];
  const float* fc1w   = (const float*)d_in[23];
  const float* fc1b   = (const float*)d_in[24];
  const float* fc2w   = (const float*)d_in[25];
  const float* fc2b   = (const float*)d_in[26];
  float* out = (float*)d_out;
  char* ws = (char*)d_ws;

  ushort* h1b = (ushort*)(ws + 0);                 // 7,602,176
  float*  A2  = (float*) (ws + 7602176);           // 14,680,064 (pwg overlays later)
  float*  pwg = (float*) (ws + 7602176);           // 7,077,888 (A2 dead by then)
  ushort* P3b = (ushort*)(ws + 22282240);          // 1,835,008
  ushort* A4b = (ushort*)(ws + 24117248);          // 3,407,872
  float*  A5  = (float*) (ws + 27525120);          // 6,291,456
  float*  P5  = (float*) (ws + 33816576);          // 1,572,864
  float*  A6p = (float*) (ws + 35389440);          // 10,485,760 (8 splits)
  float*  P6  = (float*) (ws + 45875200);          // 327,680
  float*  A7p = (float*) (ws + 46202880);          // 3,145,728 (8 splits)
  float*  featg=(float*) (ws + 49348608);          // 131,072
  ushort* Wb2 = (ushort*)(ws + 52494336);          // 73,728
  ushort* Wb4 = (ushort*)(ws + 52568064);          // 147,456
  ushort* Wb5 = (ushort*)(ws + 52715520);          // 294,912
  float*  map6= (float*) (ws + 53010432);          // 131,072
  float*  map1= (float*) (ws + 53141504);          // 1,536
  float*  map2= (float*) (ws + 53143040);          // 3,072
  float*  s1  = (float*) (ws + 53146112);
  float*  s2  = (float*) (ws + 53146368);
  int*    clsb= (int*)   (ws + 53146880);          // 1,024
  int*    order=(int*)   (ws + 53147904);          // 1,024
  int*    cntv= (int*)   (ws + 53148928);          // 320
  int*    offv= (int*)   (ws + 53149248);          // 320

  style_kernel<<<1,256,0,stream>>>(g_style, sp1, sp2, s1, s2);
  cls_sort_kernel<<<1,256,0,stream>>>(label, clsb, cntv, offv, order);
  map3_kernel<32,96,64,64><<<1,128,0,stream>>>(s1, c1w1, c1b1, map1);
  map3_kernel<64,192,128,128><<<1,256,0,stream>>>(s2, c2w, c2b, map2);
  map6_kernel<<<128,256,0,stream>>>(spaced, label, c3w1, c3b1, map6);
  repack_kernel<64,96,64><<<144,256,0,stream>>>(c1w1, Wb2);
  repack_kernel<64,64,128><<<288,256,0,stream>>>(c1w2, Wb4);
  repack_kernel<128,192,128><<<576,256,0,stream>>>(c2w, Wb5);

  // h1 (bf16)
  conv_in_kernel<<<dim3(116,8,2),256,0,stream>>>(x, in_w, in_b, h1b);
  // A2 = lrelu(conv(h1) + map1) : MFMA, f32 out
  conv_mfma<64,512,58,64,1,0><<<dim3(448,1,2),256,0,stream>>>(h1b, Wb2, map1, A2, nullptr);
  // P3 (bf16)
  pool2_bf16_kernel<<<3584,256,0,stream>>>(A2, P3b, 56, 512, 917504);
  // A4 = lrelu(conv(P3) + b) : MFMA, bf16 out
  conv_mfma<64,256,28,128,0,1><<<dim3(104,2,2),256,0,stream>>>(P3b, Wb4, c1b2, nullptr, A4b);
  // A5 = lrelu(conv(A4) + map2) : MFMA, f32 out
  conv_mfma<128,256,26,128,1,0><<<dim3(96,2,2),256,0,stream>>>(A4b, Wb5, map2, A5, nullptr);
  // P5
  pool2_kernel<<<1536,256,0,stream>>>(A5, P5, 24, 256, 393216);
  // A6 (f32 path)
  conv3_main1<128,240,12,128,128,8,8><<<dim3(5,16*8,2),256,0,stream>>>(P5, c3w1, A6p);
  combine_kernel<8,2,128,10,128><<<320,256,0,stream>>>(A6p, map6, nullptr);
  // P6
  pool2_kernel<<<320,256,0,stream>>>(A6p, P6, 10, 128, 81920);
  // A7 (f32 path)
  conv3_main1<128,128,5,64,256,4,8><<<dim3(1,64*8,2),256,0,stream>>>(P6, c3w2, A7p);
  combine_kernel<8,0,256,3,64><<<96,256,0,stream>>>(A7p, nullptr, c3b2);
  // pM
  fm_kernel<<<128,256,0,stream>>>(A7p, fm_w, fm_b, out);
  // pChar: im2col -> grouped conv -> tail
  im2col_kernel<<<6912,256,0,stream>>>(A7p, pwg);
  cd_conv_kernel<<<dim3(80,16),256,0,stream>>>(pwg, cntv, offv, order, cdw, cdb, featg);
  cd_tail_kernel<<<256,128,0,stream>>>(featg, clsb, cstyle, fc1w, fc1b, fc2w, fc2b, out + 128);
}

// Round 11
// 331.194 us; speedup vs baseline: 1.0061x; 1.0061x over previous
//
#include <hip/hip_runtime.h>
#include <hip/hip_bf16.h>

#define LEAKC 0.1f

__device__ __forceinline__ float lrelu(float v){ return v > 0.f ? v : LEAKC*v; }
__device__ __forceinline__ ushort f2b(float f){
  __hip_bfloat16 h = __float2bfloat16(f);
  return *reinterpret_cast<ushort*>(&h);
}
__device__ __forceinline__ float b2f(ushort u){
  __hip_bfloat16 h = *reinterpret_cast<__hip_bfloat16*>(&u);
  return __bfloat162float(h);
}

typedef __attribute__((ext_vector_type(8))) short bf16x8;
typedef __attribute__((ext_vector_type(4))) float f32x4;

// ---------------- setup: block0 = styles + map1 + map2; block1 = cls counting sort ----------------
__global__ __launch_bounds__(256) void setup_kernel(
    const float* __restrict__ g, const float* __restrict__ sp1, const float* __restrict__ sp2,
    const float* __restrict__ c1w1, const float* __restrict__ c1b1,
    const float* __restrict__ c2w,  const float* __restrict__ c2b,
    const float* __restrict__ label,
    float* __restrict__ map1, float* __restrict__ map2,
    int* __restrict__ clsb, int* __restrict__ cnt, int* __restrict__ off, int* __restrict__ order){
  int t = threadIdx.x;
  if (blockIdx.x == 0){
    __shared__ float s1s[64], s2s[128];
    if (t < 64){
      int b = t >> 5, j = t & 31;
      float a = 0.f;
      for (int k=0;k<256;k++) a += g[b*256+k]*sp1[j*256+k];
      s1s[t] = a;
    } else if (t < 192){
      int u = t - 64;
      int b = u >> 6, j = u & 63;
      float a = 0.f;
      for (int k=0;k<256;k++) a += g[b*256+k]*sp2[j*256+k];
      s2s[u] = a;
    }
    __syncthreads();
    if (t < 128){           // map1: COUT=64, CS=32, CTOT=96, COFF=64
      int b = t >> 6, o = t & 63;
      float S0=0.f,S1=0.f,S2=0.f;
      for (int c=0;c<32;c++){
        float s = s1s[b*32+c];
        const float* wq = c1w1 + ((size_t)o*96 + 64 + c)*9;
        S0 += s*(wq[0]+wq[3]+wq[6]);
        S1 += s*(wq[1]+wq[4]+wq[7]);
        S2 += s*(wq[2]+wq[5]+wq[8]);
      }
      float bb = c1b1[o];
      map1[t*3+0]=S1+S2+bb; map1[t*3+1]=S0+S1+S2+bb; map1[t*3+2]=S0+S1+bb;
    }
    {                        // map2: COUT=128, CS=64, CTOT=192, COFF=128
      int b = t >> 7, o = t & 127;
      float S0=0.f,S1=0.f,S2=0.f;
      for (int c=0;c<64;c++){
        float s = s2s[b*64+c];
        const float* wq = c2w + ((size_t)o*192 + 128 + c)*9;
        S0 += s*(wq[0]+wq[3]+wq[6]);
        S1 += s*(wq[1]+wq[4]+wq[7]);
        S2 += s*(wq[2]+wq[5]+wq[8]);
      }
      float bb = c2b[o];
      map2[t*3+0]=S1+S2+bb; map2[t*3+1]=S0+S1+S2+bb; map2[t*3+2]=S0+S1+bb;
    }
  } else {
    __shared__ int h[80], hoff[80];
    if (t < 80) h[t] = 0;
    __syncthreads();
    int b = t >> 7, tt = t & 127;
    const float* p = label + (tt*2 + b)*80;
    float best = p[0]; int bi = 0;
    for (int c=1;c<80;c++){ float v = p[c]; if (v > best){ best = v; bi = c; } }
    clsb[t] = bi;
    atomicAdd(&h[bi], 1);
    __syncthreads();
    if (t == 0){
      int s = 0;
      for (int e=0;e<80;e++){ hoff[e] = s; s += h[e]; }
    }
    __syncthreads();
    if (t < 80){ cnt[t] = h[t]; off[t] = hoff[t]; }
    __syncthreads();
    int rank = atomicAdd(&hoff[bi], 1);
    order[rank] = t;
  }
}

// ---------------- one repack kernel for all 5 weight tensors ----------------
__device__ __forceinline__ void pack1(int idx, const float* __restrict__ w,
                                      ushort* __restrict__ wb, int CM, int CTOT){
  int c = idx % CM; int r = idx / CM; int t = r % 9; int n = r / 9;
  wb[idx] = f2b(w[((size_t)n*CTOT + c)*9 + t]);
}
__global__ void repack_all(const float* __restrict__ c1w1, const float* __restrict__ c1w2,
                           const float* __restrict__ c2w,  const float* __restrict__ c3w1,
                           const float* __restrict__ c3w2,
                           ushort* __restrict__ Wb2, ushort* __restrict__ Wb4,
                           ushort* __restrict__ Wb5, ushort* __restrict__ Wb6,
                           ushort* __restrict__ Wb7){
  int i = blockIdx.x*256 + threadIdx.x;
  if      (i < 36864)  pack1(i,        c1w1, Wb2, 64, 96);
  else if (i < 110592) pack1(i-36864,  c1w2, Wb4, 64, 64);
  else if (i < 258048) pack1(i-110592, c2w,  Wb5, 128, 192);
  else if (i < 405504) pack1(i-258048, c3w1, Wb6, 128, 240);
  else if (i < 700416) pack1(i-405504, c3w2, Wb7, 128, 128);   // FIX: CM=128 (was 256)
}

// ---------------- input conv 7x7 -> bf16 out ----------------
__global__ void conv_in_kernel(const float* __restrict__ x,
                               const float* __restrict__ wgt,
                               const float* __restrict__ bias,
                               ushort* __restrict__ out){
  int hw = blockIdx.x*256 + threadIdx.x;
  int y = hw >> 9, w = hw & 511;
  int b = blockIdx.z;
  int o0 = blockIdx.y * 8;
  float acc[8];
  #pragma unroll
  for (int i=0;i<8;i++) acc[i] = bias[o0+i];
  for (int kh=0;kh<7;kh++){
    const float* ip = x + (b*64 + y + kh)*512;
    #pragma unroll
    for (int kw=0;kw<7;kw++){
      int wi = w + kw - 3;
      float v = (wi>=0 && wi<512) ? ip[wi] : 0.f;
      #pragma unroll
      for (int i=0;i<8;i++) acc[i] += v * wgt[(o0+i)*49 + kh*7 + kw];
    }
  }
  #pragma unroll
  for (int i=0;i<8;i++)
    out[((b*64 + o0+i)*58 + y)*512 + w] = f2b(lrelu(acc[i]));
}

// ---------------- MFMA conv: 3x3, pad(0,1), BM=64, BN=64, K=CM*9 ----------------
// MODE 0: +bias[n]; MODE 1: 3-value map (b,n,{L,M,R}); MODE 2: full (b,n,w) map. OUTBF: bf16 out.
template<int CM,int WID,int HIN,int COUT,int MODE,int OUTBF>
__global__ __launch_bounds__(256) void conv_mfma(
    const ushort* __restrict__ in,   // bf16 (2,CM,HIN,WID)
    const ushort* __restrict__ Wb,   // bf16 (COUT, CM*9) packed [t*CM+c]
    const float*  __restrict__ mb,
    float* __restrict__ outf,
    ushort* __restrict__ outh){
  constexpr int HOUT = HIN - 2;
  constexpr int KTOT = CM*9;
  constexpr int SLABS = CM/32;
  constexpr int NST = 3*SLABS;
  __shared__ ushort A[2][66][40];
  int tid = threadIdx.x, lane = tid & 63, wave = tid >> 6;
  int mt = blockIdx.x;
  int y  = mt / (WID/64), w0 = (mt % (WID/64))*64;
  int n0 = blockIdx.y*64;
  int b  = blockIdx.z;

  f32x4 acc[4];
  #pragma unroll
  for (int nf=0;nf<4;nf++) acc[nf] = (f32x4){0.f,0.f,0.f,0.f};

  auto stage = [&](int s, int bufi){
    int kh = s / SLABS;
    int c0 = (s % SLABS)*32;
    const ushort* base = in + ((size_t)(b*CM + c0)*HIN + (y+kh))*WID;
    int c2 = (tid & 15)*2, m0v = (tid >> 4)*2*2;
    const ushort* p0 = base + (size_t)c2*HIN*WID + w0 + m0v;
    const ushort* p1 = p0 + (size_t)HIN*WID;
    ushort4 va = *(const ushort4*)p0;
    ushort4 vb = *(const ushort4*)p1;
    uint* dst = (uint*)&A[bufi][1+m0v][c2];
    dst[0]  = (uint)va.x | ((uint)vb.x << 16);
    dst[20] = (uint)va.y | ((uint)vb.y << 16);
    dst[40] = (uint)va.z | ((uint)vb.z << 16);
    dst[60] = (uint)va.w | ((uint)vb.w << 16);
    if (tid < 64){
      int c = tid & 31, side = tid >> 5;
      int w = side ? (w0 + 64) : (w0 - 1);
      ushort v = 0;
      if (w >= 0 && w < WID) v = base[(size_t)c*HIN*WID + w];
      A[bufi][side ? 65 : 0][c] = v;
    }
  };

  stage(0, 0);
  __syncthreads();
  for (int s = 0; s < NST; ++s){
    int cur = s & 1;
    if (s + 1 < NST) stage(s+1, cur ^ 1);
    int kh = s / SLABS;
    int c0 = (s % SLABS)*32;
    #pragma unroll
    for (int kw = 0; kw < 3; ++kw){
      bf16x8 a = *(bf16x8*)&A[cur][wave*16 + (lane & 15) + kw][(lane >> 4)*8];
      #pragma unroll
      for (int nf = 0; nf < 4; ++nf){
        const ushort* wp = Wb + (size_t)(n0 + nf*16 + (lane & 15))*KTOT
                              + (kh*3 + kw)*CM + c0 + (lane >> 4)*8;
        bf16x8 bb = *(const bf16x8*)wp;
        acc[nf] = __builtin_amdgcn_mfma_f32_16x16x32_bf16(a, bb, acc[nf], 0, 0, 0);
      }
    }
    __syncthreads();
  }

  int mrow = wave*16 + ((lane >> 4) << 2);
  int w = w0 + mrow;
  #pragma unroll
  for (int nf = 0; nf < 4; ++nf){
    int n = n0 + nf*16 + (lane & 15);
    float r0 = acc[nf][0], r1 = acc[nf][1], r2 = acc[nf][2], r3 = acc[nf][3];
    if (MODE == 0){
      float bb = mb[n];
      r0 += bb; r1 += bb; r2 += bb; r3 += bb;
    } else if (MODE == 1){
      const float* m3 = mb + (size_t)(b*COUT + n)*3;
      float mL = m3[0], mM = m3[1], mR = m3[2];
      r0 += (w == 0) ? mL : ((w   == WID-1) ? mR : mM);
      r1 += (w+1 == WID-1) ? mR : mM;
      r2 += (w+2 == WID-1) ? mR : mM;
      r3 += (w+3 == WID-1) ? mR : mM;
    } else {
      const float* m6 = mb + ((size_t)(b*COUT + n))*WID + w;
      r0 += m6[0]; r1 += m6[1]; r2 += m6[2]; r3 += m6[3];
    }
    r0 = lrelu(r0); r1 = lrelu(r1); r2 = lrelu(r2); r3 = lrelu(r3);
    size_t off = ((size_t)(b*COUT + n)*HOUT + y)*WID + w;
    if (OUTBF){
      ushort4 o = make_ushort4(f2b(r0), f2b(r1), f2b(r2), f2b(r3));
      *(ushort4*)(outh + off) = o;
    } else {
      *(float4*)(outf + off) = make_float4(r0, r1, r2, r3);
    }
  }
}

// ---------------- A6 column map (includes bias) ----------------
__global__ void map6_kernel(const float* __restrict__ spaced,
                            const float* __restrict__ label,
                            const float* __restrict__ wgt,
                            const float* __restrict__ bias,
                            float* __restrict__ mapv){
  int n = blockIdx.x*256 + threadIdx.x;
  int w = n & 127, o = (n >> 7) & 127, b = n >> 14;
  float a = bias[o];
  #pragma unroll
  for (int t=0;t<3;t++){
    int j = w + t - 1;
    if (j < 0 || j >= 128) continue;
    const float* sp = spaced + (j*2 + b)*32;
    const float* lb = label + (j*2 + b)*80;
    for (int c=0;c<32;c++){
      const float* wq = wgt + ((size_t)o*240 + 128 + c)*9 + t;
      a += sp[c]*(wq[0]+wq[3]+wq[6]);
    }
    for (int c=0;c<80;c++){
      const float* wq = wgt + ((size_t)o*240 + 160 + c)*9 + t;
      a += lb[c]*(wq[0]+wq[3]+wq[6]);
    }
  }
  mapv[n] = a;
}

// ---------------- 2x2 mean pool (f32 -> bf16) ----------------
__global__ void pool2_bf16_kernel(const float* __restrict__ in, ushort* __restrict__ out,
                                  int H, int W, int total){
  int n = blockIdx.x*256 + threadIdx.x;
  if (n >= total) return;
  int Wo = W >> 1;
  int wo = n % Wo;
  int r = n / Wo;
  int Ho = H >> 1;
  int ho = r % Ho;
  int bc = r / Ho;
  const float* p = in + (bc*H + 2*ho)*W + 2*wo;
  out[n] = f2b(0.25f*(p[0] + p[1] + p[W] + p[W+1]));
}

// ---------------- 2x2 mean pool (bf16 -> bf16) ----------------
__global__ void pool2_h2h_kernel(const ushort* __restrict__ in, ushort* __restrict__ out,
                                 int H, int W, int total){
  int n = blockIdx.x*256 + threadIdx.x;
  if (n >= total) return;
  int Wo = W >> 1;
  int wo = n % Wo;
  int r = n / Wo;
  int Ho = H >> 1;
  int ho = r % Ho;
  int bc = r / Ho;
  const ushort* p = in + (bc*H + 2*ho)*W + 2*wo;
  out[n] = f2b(0.25f*(b2f(p[0]) + b2f(p[1]) + b2f(p[W]) + b2f(p[W+1])));
}

// ---------------- pM ----------------
__global__ __launch_bounds__(256) void fm_kernel(const float* __restrict__ A7,
                          const float* __restrict__ fw,
                          const float* __restrict__ fb,
                          float* __restrict__ out){
  __shared__ float red[4];
  int n = blockIdx.x;
  int b = n >> 6, w = n & 63;
  int c = threadIdx.x;
  float a = 0.f;
  #pragma unroll
  for (int r=0;r<3;r++){
    const float* ip = A7 + ((b*256+c)*3+r)*64;
    const float* wp = fw + (c*3+r)*3;
    #pragma unroll
    for (int kw=0;kw<3;kw++){
      int wi = w + kw - 1;
      if (wi>=0 && wi<64) a += ip[wi]*wp[kw];
    }
  }
  #pragma unroll
  for (int off=32; off>0; off>>=1) a += __shfl_down(a, off, 64);
  if ((threadIdx.x & 63) == 0) red[threadIdx.x>>6] = a;
  __syncthreads();
  if (threadIdx.x == 0) out[n] = red[0]+red[1]+red[2]+red[3] + fb[0];
}

// ---------------- im2col: pwg[n][j][d] (d = c*9 + r*3 + kw) ----------------
__global__ void im2col_kernel(const float* __restrict__ A7, float* __restrict__ pwg){
  int i = blockIdx.x*256 + threadIdx.x;
  if (i >= 256*3*2304) return;
  int d = i % 2304; int rj = i / 2304; int j = rj % 3; int n = rj / 3;
  int b = n >> 7, t = n & 127; int idx = t >> 1;
  int c = d / 9, rem = d - c*9, r = rem / 3, kw = rem - r*3;
  int col = idx - 2 + kw + j;
  pwg[i] = (col >= 0 && col < 64) ? A7[((size_t)(b*256 + c)*3 + r)*64 + col] : 0.f;
}

// ---------------- cd conv v4: class-grouped, register patches, no LDS / no barriers ----------------
__global__ __launch_bounds__(256) void cd_conv_kernel(
    const float* __restrict__ pwg,    // (256,3,2304)
    const int*   __restrict__ cnt,    // (80)
    const int*   __restrict__ offv,   // (80)
    const int*   __restrict__ order,  // (256)
    const float* __restrict__ Wc,     // (80,128,2304)
    const float* __restrict__ bcv,    // (80,128)
    float* __restrict__ featg)        // (256,128)
{
  int e = blockIdx.x, og = blockIdx.y;
  int m = cnt[e];
  if (m == 0) return;
  int base = offv[e];
  int tid = threadIdx.x, lane = tid & 63, wave = tid >> 6;
  int out0 = og*8 + wave*2;

  float4 wr[2][9];
  #pragma unroll
  for (int oi=0;oi<2;oi++){
    const float4* wp = (const float4*)(Wc + ((size_t)e*128 + out0 + oi)*2304);
    #pragma unroll
    for (int k=0;k<9;k++) wr[oi][k] = wp[k*64 + lane];
  }
  float b0 = bcv[e*128 + out0], b1v = bcv[e*128 + out0 + 1];

  for (int s = 0; s < m; ++s){
    int n = order[base + s];
    const float4* src = (const float4*)(pwg + (size_t)n*3*2304) + lane;
    float a[2][3] = {{0.f,0.f,0.f},{0.f,0.f,0.f}};
    #pragma unroll
    for (int j = 0; j < 3; ++j){
      #pragma unroll
      for (int k = 0; k < 9; ++k){
        float4 p = src[j*576 + k*64];
        #pragma unroll
        for (int oi = 0; oi < 2; ++oi){
          float4 w4 = wr[oi][k];
          a[oi][j] += w4.x*p.x + w4.y*p.y + w4.z*p.z + w4.w*p.w;
        }
      }
    }
    #pragma unroll
    for (int off = 32; off > 0; off >>= 1){
      #pragma unroll
      for (int oi = 0; oi < 2; ++oi){
        a[oi][0] += __shfl_down(a[oi][0], off, 64);
        a[oi][1] += __shfl_down(a[oi][1], off, 64);
        a[oi][2] += __shfl_down(a[oi][2], off, 64);
      }
    }
    if (lane == 0){
      featg[(size_t)n*128 + out0] =
        (lrelu(a[0][0]+b0) + lrelu(a[0][1]+b0) + lrelu(a[0][2]+b0)) * (1.f/3.f);
      featg[(size_t)n*128 + out0 + 1] =
        (lrelu(a[1][0]+b1v) + lrelu(a[1][1]+b1v) + lrelu(a[1][2]+b1v)) * (1.f/3.f);
    }
  }
}

// ---------------- cd tail ----------------
__global__ __launch_bounds__(128) void cd_tail_kernel(
    const float* __restrict__ featg,
    const int*   __restrict__ clsb,
    const float* __restrict__ cstyle,
    const float* __restrict__ W1,
    const float* __restrict__ b1,
    const float* __restrict__ W2,
    const float* __restrict__ b2,
    float* __restrict__ pChar)
{
  __shared__ float feat[160];
  __shared__ float red2[2];
  int n = blockIdx.x, tid = threadIdx.x;
  int b = n >> 7;
  int e = clsb[n];
  int o = tid;
  feat[o] = featg[(size_t)n*128 + o];
  if (tid < 32) feat[128+tid] = cstyle[(b*80 + e)*32 + tid];
  __syncthreads();

  float s = b1[e*128 + o];
  for (int d=0;d<160;d++) s += feat[d]*W1[(e*160 + d)*128 + o];
  float h = s > 0.f ? s : 0.f;
  float contrib = h * W2[e*128 + o];
  #pragma unroll
  for (int off=32; off>0; off>>=1) contrib += __shfl_down(contrib, off, 64);
  if ((tid & 63) == 0) red2[tid>>6] = contrib;
  __syncthreads();
  if (tid == 0) pChar[n] = red2[0] + red2[1] + b2[e];
}

extern "C" void kernel_launch(void* const* d_in, const int* in_sizes, int n_in,
                              void* d_out, int out_size, void* d_ws, size_t ws_size,
                              hipStream_t stream){
  (void)in_sizes; (void)n_in; (void)out_size; (void)ws_size;
  const float* x      = (const float*)d_in[0];
  const float* label  = (const float*)d_in[1];
  const float* g_style= (const float*)d_in[2];
  const float* spaced = (const float*)d_in[3];
  const float* cstyle = (const float*)d_in[4];
  const float* sp1    = (const float*)d_in[5];
  const float* sp2    = (const float*)d_in[6];
  const float* in_w   = (const float*)d_in[7];
  const float* in_b   = (const float*)d_in[8];
  const float* c1w1   = (const float*)d_in[9];
  const float* c1b1   = (const float*)d_in[10];
  const float* c1w2   = (const float*)d_in[11];
  const float* c1b2   = (const float*)d_in[12];
  const float* c2w    = (const float*)d_in[13];
  const float* c2b    = (const float*)d_in[14];
  const float* c3w1   = (const float*)d_in[15];
  const float* c3b1   = (const float*)d_in[16];
  const float* c3w2   = (const float*)d_in[17];
  const float* c3b2   = (const float*)d_in[18];
  const float* fm_w   = (const float*)d_in[19];
  const float* fm_b   = (const float*)d_in[20];
  const float* cdw    = (const float*)d_in[21];
  const float* cdb    = (const float*)d_in[22];
  const float* fc1w   = (const float*)d_in[23];
  const float* fc1b   = (const float*)d_in[24];
  const float* fc2w   = (const float*)d_in[25];
  const float* fc2b   = (const float*)d_in[26];
  float* out = (float*)d_out;
  char* ws = (char*)d_ws;

  ushort* h1b  = (ushort*)(ws + 0);                // 7,602,176
  float*  A2   = (float*) (ws + 7602176);          // 14,680,064 (pwg overlays later)
  float*  pwg  = (float*) (ws + 7602176);          // 7,077,888
  ushort* P3b  = (ushort*)(ws + 22282240);         // 1,835,008
  ushort* A4b  = (ushort*)(ws + 24117248);         // 3,407,872
  float*  A5   = (float*) (ws + 27525120);         // 6,291,456
  ushort* P5b  = (ushort*)(ws + 33816576);         // 786,432
  ushort* A6b  = (ushort*)(ws + 34603008);         // 655,360
  ushort* P6b  = (ushort*)(ws + 35258368);         // 163,840
  float*  A7   = (float*) (ws + 35422208);         // 1,572,864
  float*  featg= (float*) (ws + 36995072);         // 131,072
  ushort* Wb2  = (ushort*)(ws + 37126144);         // 73,728
  ushort* Wb4  = (ushort*)(ws + 37199872);         // 147,456
  ushort* Wb5  = (ushort*)(ws + 37347328);         // 294,912
  ushort* Wb6  = (ushort*)(ws + 37642240);         // 294,912
  ushort* Wb7  = (ushort*)(ws + 37937152);         // 589,824
  float*  map6 = (float*) (ws + 38526976);         // 131,072
  float*  map1 = (float*) (ws + 38658048);         // 1,536
  float*  map2 = (float*) (ws + 38659584);         // 3,072
  int*    clsb = (int*)   (ws + 38663424);         // 1,024
  int*    order= (int*)   (ws + 38664448);         // 1,024
  int*    cntv = (int*)   (ws + 38665472);         // 320
  int*    offv = (int*)   (ws + 38665792);         // 320

  setup_kernel<<<2,256,0,stream>>>(g_style, sp1, sp2, c1w1, c1b1, c2w, c2b, label,
                                   map1, map2, clsb, cntv, offv, order);
  repack_all<<<2736,256,0,stream>>>(c1w1, c1w2, c2w, c3w1, c3w2, Wb2, Wb4, Wb5, Wb6, Wb7);
  map6_kernel<<<128,256,0,stream>>>(spaced, label, c3w1, c3b1, map6);

  // h1 (bf16)
  conv_in_kernel<<<dim3(116,8,2),256,0,stream>>>(x, in_w, in_b, h1b);
  // A2 = lrelu(conv(h1) + map1) : MFMA, f32 out
  conv_mfma<64,512,58,64,1,0><<<dim3(448,1,2),256,0,stream>>>(h1b, Wb2, map1, A2, nullptr);
  // P3 (bf16)
  pool2_bf16_kernel<<<3584,256,0,stream>>>(A2, P3b, 56, 512, 917504);
  // A4 = lrelu(conv(P3) + b) : MFMA, bf16 out
  conv_mfma<64,256,28,128,0,1><<<dim3(104,2,2),256,0,stream>>>(P3b, Wb4, c1b2, nullptr, A4b);
  // A5 = lrelu(conv(A4) + map2) : MFMA, f32 out
  conv_mfma<128,256,26,128,1,0><<<dim3(96,2,2),256,0,stream>>>(A4b, Wb5, map2, A5, nullptr);
  // P5 (bf16)
  pool2_bf16_kernel<<<1536,256,0,stream>>>(A5, P5b, 24, 256, 393216);
  // A6 = lrelu(conv(P5) + map6) : MFMA MODE2, bf16 out
  conv_mfma<128,128,12,128,2,1><<<dim3(20,2,2),256,0,stream>>>(P5b, Wb6, map6, nullptr, A6b);
  // P6 (bf16 -> bf16)
  pool2_h2h_kernel<<<320,256,0,stream>>>(A6b, P6b, 10, 128, 81920);
  // A7 = lrelu(conv(P6) + b) : MFMA, f32 out
  conv_mfma<128,64,5,256,0,0><<<dim3(3,4,2),256,0,stream>>>(P6b, Wb7, c3b2, A7, nullptr);
  // pM
  fm_kernel<<<128,256,0,stream>>>(A7, fm_w, fm_b, out);
  // pChar: im2col -> grouped conv -> tail
  im2col_kernel<<<6912,256,0,stream>>>(A7, pwg);
  cd_conv_kernel<<<dim3(80,16),256,0,stream>>>(pwg, cntv, offv, order, cdw, cdb, featg);
  cd_tail_kernel<<<256,128,0,stream>>>(featg, clsb, cstyle, fc1w, fc1b, fc2w, fc2b, out + 128);
}

// Round 12
// 329.667 us; speedup vs baseline: 1.0108x; 1.0046x over previous
//
#include <hip/hip_runtime.h>
#include <hip/hip_bf16.h>

#define LEAKC 0.1f

__device__ __forceinline__ float lrelu(float v){ return v > 0.f ? v : LEAKC*v; }
__device__ __forceinline__ ushort f2b(float f){
  __hip_bfloat16 h = __float2bfloat16(f);
  return *reinterpret_cast<ushort*>(&h);
}
__device__ __forceinline__ float b2f(ushort u){
  __hip_bfloat16 h = *reinterpret_cast<__hip_bfloat16*>(&u);
  return __bfloat162float(h);
}

typedef __attribute__((ext_vector_type(8))) short bf16x8;
typedef __attribute__((ext_vector_type(4))) float f32x4;

// ---------------- setup: block0 = styles + map1 + map2; block1 = cls counting sort ----------------
__global__ __launch_bounds__(256) void setup_kernel(
    const float* __restrict__ g, const float* __restrict__ sp1, const float* __restrict__ sp2,
    const float* __restrict__ c1w1, const float* __restrict__ c1b1,
    const float* __restrict__ c2w,  const float* __restrict__ c2b,
    const float* __restrict__ label,
    float* __restrict__ map1, float* __restrict__ map2,
    int* __restrict__ clsb, int* __restrict__ cnt, int* __restrict__ off, int* __restrict__ order){
  int t = threadIdx.x;
  if (blockIdx.x == 0){
    __shared__ float s1s[64], s2s[128];
    if (t < 64){
      int b = t >> 5, j = t & 31;
      float a = 0.f;
      for (int k=0;k<256;k++) a += g[b*256+k]*sp1[j*256+k];
      s1s[t] = a;
    } else if (t < 192){
      int u = t - 64;
      int b = u >> 6, j = u & 63;
      float a = 0.f;
      for (int k=0;k<256;k++) a += g[b*256+k]*sp2[j*256+k];
      s2s[u] = a;
    }
    __syncthreads();
    if (t < 128){           // map1
      int b = t >> 6, o = t & 63;
      float S0=0.f,S1=0.f,S2=0.f;
      for (int c=0;c<32;c++){
        float s = s1s[b*32+c];
        const float* wq = c1w1 + ((size_t)o*96 + 64 + c)*9;
        S0 += s*(wq[0]+wq[3]+wq[6]);
        S1 += s*(wq[1]+wq[4]+wq[7]);
        S2 += s*(wq[2]+wq[5]+wq[8]);
      }
      float bb = c1b1[o];
      map1[t*3+0]=S1+S2+bb; map1[t*3+1]=S0+S1+S2+bb; map1[t*3+2]=S0+S1+bb;
    }
    {                        // map2
      int b = t >> 7, o = t & 127;
      float S0=0.f,S1=0.f,S2=0.f;
      for (int c=0;c<64;c++){
        float s = s2s[b*64+c];
        const float* wq = c2w + ((size_t)o*192 + 128 + c)*9;
        S0 += s*(wq[0]+wq[3]+wq[6]);
        S1 += s*(wq[1]+wq[4]+wq[7]);
        S2 += s*(wq[2]+wq[5]+wq[8]);
      }
      float bb = c2b[o];
      map2[t*3+0]=S1+S2+bb; map2[t*3+1]=S0+S1+S2+bb; map2[t*3+2]=S0+S1+bb;
    }
  } else {
    __shared__ int h[80], hoff[80];
    if (t < 80) h[t] = 0;
    __syncthreads();
    int b = t >> 7, tt = t & 127;
    const float* p = label + (tt*2 + b)*80;
    float best = p[0]; int bi = 0;
    for (int c=1;c<80;c++){ float v = p[c]; if (v > best){ best = v; bi = c; } }
    clsb[t] = bi;
    atomicAdd(&h[bi], 1);
    __syncthreads();
    if (t == 0){
      int s = 0;
      for (int e=0;e<80;e++){ hoff[e] = s; s += h[e]; }
    }
    __syncthreads();
    if (t < 80){ cnt[t] = h[t]; off[t] = hoff[t]; }
    __syncthreads();
    int rank = atomicAdd(&hoff[bi], 1);
    order[rank] = t;
  }
}

// ---------------- one repack kernel for all 5 weight tensors ----------------
__device__ __forceinline__ void pack1(int idx, const float* __restrict__ w,
                                      ushort* __restrict__ wb, int CM, int CTOT){
  int c = idx % CM; int r = idx / CM; int t = r % 9; int n = r / 9;
  wb[idx] = f2b(w[((size_t)n*CTOT + c)*9 + t]);
}
__global__ void repack_all(const float* __restrict__ c1w1, const float* __restrict__ c1w2,
                           const float* __restrict__ c2w,  const float* __restrict__ c3w1,
                           const float* __restrict__ c3w2,
                           ushort* __restrict__ Wb2, ushort* __restrict__ Wb4,
                           ushort* __restrict__ Wb5, ushort* __restrict__ Wb6,
                           ushort* __restrict__ Wb7){
  int i = blockIdx.x*256 + threadIdx.x;
  if      (i < 36864)  pack1(i,        c1w1, Wb2, 64, 96);
  else if (i < 110592) pack1(i-36864,  c1w2, Wb4, 64, 64);
  else if (i < 258048) pack1(i-110592, c2w,  Wb5, 128, 192);
  else if (i < 405504) pack1(i-258048, c3w1, Wb6, 128, 240);
  else if (i < 700416) pack1(i-405504, c3w2, Wb7, 128, 128);
}

// ---------------- input conv 7x7 -> bf16 out ----------------
__global__ void conv_in_kernel(const float* __restrict__ x,
                               const float* __restrict__ wgt,
                               const float* __restrict__ bias,
                               ushort* __restrict__ out){
  int hw = blockIdx.x*256 + threadIdx.x;
  int y = hw >> 9, w = hw & 511;
  int b = blockIdx.z;
  int o0 = blockIdx.y * 8;
  float acc[8];
  #pragma unroll
  for (int i=0;i<8;i++) acc[i] = bias[o0+i];
  for (int kh=0;kh<7;kh++){
    const float* ip = x + (b*64 + y + kh)*512;
    #pragma unroll
    for (int kw=0;kw<7;kw++){
      int wi = w + kw - 3;
      float v = (wi>=0 && wi<512) ? ip[wi] : 0.f;
      #pragma unroll
      for (int i=0;i<8;i++) acc[i] += v * wgt[(o0+i)*49 + kh*7 + kw];
    }
  }
  #pragma unroll
  for (int i=0;i<8;i++)
    out[((b*64 + o0+i)*58 + y)*512 + w] = f2b(lrelu(acc[i]));
}

// ---------------- MFMA conv: 3x3, pad(0,1), BM=64, BN=64, K=CM*9 ----------------
template<int CM,int WID,int HIN,int COUT,int MODE,int OUTBF>
__global__ __launch_bounds__(256) void conv_mfma(
    const ushort* __restrict__ in,
    const ushort* __restrict__ Wb,
    const float*  __restrict__ mb,
    float* __restrict__ outf,
    ushort* __restrict__ outh){
  constexpr int HOUT = HIN - 2;
  constexpr int KTOT = CM*9;
  constexpr int SLABS = CM/32;
  constexpr int NST = 3*SLABS;
  __shared__ ushort A[2][66][40];
  int tid = threadIdx.x, lane = tid & 63, wave = tid >> 6;
  int mt = blockIdx.x;
  int y  = mt / (WID/64), w0 = (mt % (WID/64))*64;
  int n0 = blockIdx.y*64;
  int b  = blockIdx.z;

  f32x4 acc[4];
  #pragma unroll
  for (int nf=0;nf<4;nf++) acc[nf] = (f32x4){0.f,0.f,0.f,0.f};

  auto stage = [&](int s, int bufi){
    int kh = s / SLABS;
    int c0 = (s % SLABS)*32;
    const ushort* base = in + ((size_t)(b*CM + c0)*HIN + (y+kh))*WID;
    int c2 = (tid & 15)*2, m0v = (tid >> 4)*2*2;
    const ushort* p0 = base + (size_t)c2*HIN*WID + w0 + m0v;
    const ushort* p1 = p0 + (size_t)HIN*WID;
    ushort4 va = *(const ushort4*)p0;
    ushort4 vb = *(const ushort4*)p1;
    uint* dst = (uint*)&A[bufi][1+m0v][c2];
    dst[0]  = (uint)va.x | ((uint)vb.x << 16);
    dst[20] = (uint)va.y | ((uint)vb.y << 16);
    dst[40] = (uint)va.z | ((uint)vb.z << 16);
    dst[60] = (uint)va.w | ((uint)vb.w << 16);
    if (tid < 64){
      int c = tid & 31, side = tid >> 5;
      int w = side ? (w0 + 64) : (w0 - 1);
      ushort v = 0;
      if (w >= 0 && w < WID) v = base[(size_t)c*HIN*WID + w];
      A[bufi][side ? 65 : 0][c] = v;
    }
  };

  stage(0, 0);
  __syncthreads();
  for (int s = 0; s < NST; ++s){
    int cur = s & 1;
    if (s + 1 < NST) stage(s+1, cur ^ 1);
    int kh = s / SLABS;
    int c0 = (s % SLABS)*32;
    #pragma unroll
    for (int kw = 0; kw < 3; ++kw){
      bf16x8 a = *(bf16x8*)&A[cur][wave*16 + (lane & 15) + kw][(lane >> 4)*8];
      #pragma unroll
      for (int nf = 0; nf < 4; ++nf){
        const ushort* wp = Wb + (size_t)(n0 + nf*16 + (lane & 15))*KTOT
                              + (kh*3 + kw)*CM + c0 + (lane >> 4)*8;
        bf16x8 bb = *(const bf16x8*)wp;
        acc[nf] = __builtin_amdgcn_mfma_f32_16x16x32_bf16(a, bb, acc[nf], 0, 0, 0);
      }
    }
    __syncthreads();
  }

  int mrow = wave*16 + ((lane >> 4) << 2);
  int w = w0 + mrow;
  #pragma unroll
  for (int nf = 0; nf < 4; ++nf){
    int n = n0 + nf*16 + (lane & 15);
    float r0 = acc[nf][0], r1 = acc[nf][1], r2 = acc[nf][2], r3 = acc[nf][3];
    if (MODE == 0){
      float bb = mb[n];
      r0 += bb; r1 += bb; r2 += bb; r3 += bb;
    } else if (MODE == 1){
      const float* m3 = mb + (size_t)(b*COUT + n)*3;
      float mL = m3[0], mM = m3[1], mR = m3[2];
      r0 += (w == 0) ? mL : ((w   == WID-1) ? mR : mM);
      r1 += (w+1 == WID-1) ? mR : mM;
      r2 += (w+2 == WID-1) ? mR : mM;
      r3 += (w+3 == WID-1) ? mR : mM;
    } else {
      const float* m6 = mb + ((size_t)(b*COUT + n))*WID + w;
      r0 += m6[0]; r1 += m6[1]; r2 += m6[2]; r3 += m6[3];
    }
    r0 = lrelu(r0); r1 = lrelu(r1); r2 = lrelu(r2); r3 = lrelu(r3);
    size_t off = ((size_t)(b*COUT + n)*HOUT + y)*WID + w;
    if (OUTBF){
      ushort4 o = make_ushort4(f2b(r0), f2b(r1), f2b(r2), f2b(r3));
      *(ushort4*)(outh + off) = o;
    } else {
      *(float4*)(outf + off) = make_float4(r0, r1, r2, r3);
    }
  }
}

// ---------------- A6 column map (includes bias) ----------------
__global__ void map6_kernel(const float* __restrict__ spaced,
                            const float* __restrict__ label,
                            const float* __restrict__ wgt,
                            const float* __restrict__ bias,
                            float* __restrict__ mapv){
  int n = blockIdx.x*256 + threadIdx.x;
  int w = n & 127, o = (n >> 7) & 127, b = n >> 14;
  float a = bias[o];
  #pragma unroll
  for (int t=0;t<3;t++){
    int j = w + t - 1;
    if (j < 0 || j >= 128) continue;
    const float* sp = spaced + (j*2 + b)*32;
    const float* lb = label + (j*2 + b)*80;
    for (int c=0;c<32;c++){
      const float* wq = wgt + ((size_t)o*240 + 128 + c)*9 + t;
      a += sp[c]*(wq[0]+wq[3]+wq[6]);
    }
    for (int c=0;c<80;c++){
      const float* wq = wgt + ((size_t)o*240 + 160 + c)*9 + t;
      a += lb[c]*(wq[0]+wq[3]+wq[6]);
    }
  }
  mapv[n] = a;
}

// ---------------- 2x2 mean pool (bf16 -> bf16) ----------------
__global__ void pool2_h2h_kernel(const ushort* __restrict__ in, ushort* __restrict__ out,
                                 int H, int W, int total){
  int n = blockIdx.x*256 + threadIdx.x;
  if (n >= total) return;
  int Wo = W >> 1;
  int wo = n % Wo;
  int r = n / Wo;
  int Ho = H >> 1;
  int ho = r % Ho;
  int bc = r / Ho;
  const ushort* p = in + (bc*H + 2*ho)*W + 2*wo;
  out[n] = f2b(0.25f*(b2f(p[0]) + b2f(p[1]) + b2f(p[W]) + b2f(p[W+1])));
}

// ---------------- pM ----------------
__global__ __launch_bounds__(256) void fm_kernel(const float* __restrict__ A7,
                          const float* __restrict__ fw,
                          const float* __restrict__ fb,
                          float* __restrict__ out){
  __shared__ float red[4];
  int n = blockIdx.x;
  int b = n >> 6, w = n & 63;
  int c = threadIdx.x;
  float a = 0.f;
  #pragma unroll
  for (int r=0;r<3;r++){
    const float* ip = A7 + ((b*256+c)*3+r)*64;
    const float* wp = fw + (c*3+r)*3;
    #pragma unroll
    for (int kw=0;kw<3;kw++){
      int wi = w + kw - 1;
      if (wi>=0 && wi<64) a += ip[wi]*wp[kw];
    }
  }
  #pragma unroll
  for (int off=32; off>0; off>>=1) a += __shfl_down(a, off, 64);
  if ((threadIdx.x & 63) == 0) red[threadIdx.x>>6] = a;
  __syncthreads();
  if (threadIdx.x == 0) out[n] = red[0]+red[1]+red[2]+red[3] + fb[0];
}

// ---------------- im2col -> bf16: pwgh[n][j][d] (d = c*9 + r*3 + kw) ----------------
__global__ void im2col_kernel(const float* __restrict__ A7, ushort* __restrict__ pwgh){
  int i = blockIdx.x*256 + threadIdx.x;
  if (i >= 256*3*2304) return;
  int d = i % 2304; int rj = i / 2304; int j = rj % 3; int n = rj / 3;
  int b = n >> 7, t = n & 127; int idx = t >> 1;
  int c = d / 9, rem = d - c*9, r = rem / 3, kw = rem - r*3;
  int col = idx - 2 + kw + j;
  pwgh[i] = (col >= 0 && col < 64) ? f2b(A7[((size_t)(b*256 + c)*3 + r)*64 + col]) : (ushort)0;
}

// ---------------- cd conv v5: class-grouped, LDS-shared bf16 patch, double-buffered ----------------
// grid (80,16): block = class e, 8 outputs; wave owns 2 (f32 weights in 72 VGPR).
// Per sample: stage next patch (13.8 KB) into buf^1 while computing from buf; 1 barrier/sample.
__global__ __launch_bounds__(256) void cd_conv_kernel(
    const ushort* __restrict__ pwgh,  // (256,3,2304) bf16
    const int*   __restrict__ cnt,    // (80)
    const int*   __restrict__ offv,   // (80)
    const int*   __restrict__ order,  // (256)
    const float* __restrict__ Wc,     // (80,128,2304)
    const float* __restrict__ bcv,    // (80,128)
    float* __restrict__ featg)        // (256,128)
{
  __shared__ ushort pw[2][3*2304];    // 2 x 13,824 B
  int e = blockIdx.x, og = blockIdx.y;
  int m = cnt[e];
  if (m == 0) return;
  int base = offv[e];
  int tid = threadIdx.x, lane = tid & 63, wave = tid >> 6;
  int out0 = og*8 + wave*2;

  float4 wr[2][9];
  #pragma unroll
  for (int oi=0;oi<2;oi++){
    const float4* wp = (const float4*)(Wc + ((size_t)e*128 + out0 + oi)*2304);
    #pragma unroll
    for (int k=0;k<9;k++) wr[oi][k] = wp[k*64 + lane];
  }
  float b0 = bcv[e*128 + out0], b1v = bcv[e*128 + out0 + 1];

  auto stagep = [&](int n, int bufi){
    const ushort4* src = (const ushort4*)(pwgh + (size_t)n*3*2304);
    ushort4* dst = (ushort4*)pw[bufi];
    #pragma unroll 2
    for (int i = tid; i < 1728; i += 256) dst[i] = src[i];
  };

  stagep(order[base], 0);
  __syncthreads();

  for (int s = 0; s < m; ++s){
    int cur = s & 1;
    if (s + 1 < m) stagep(order[base + s + 1], cur ^ 1);

    const ushort* pb = pw[cur];
    float a[2][3] = {{0.f,0.f,0.f},{0.f,0.f,0.f}};
    #pragma unroll
    for (int k = 0; k < 9; ++k){
      int d0 = (k*64 + lane)*4;
      #pragma unroll
      for (int j = 0; j < 3; ++j){
        uint2 q = *(const uint2*)&pb[j*2304 + d0];
        float p0 = __uint_as_float(q.x << 16);
        float p1 = __uint_as_float(q.x & 0xffff0000u);
        float p2 = __uint_as_float(q.y << 16);
        float p3 = __uint_as_float(q.y & 0xffff0000u);
        #pragma unroll
        for (int oi = 0; oi < 2; ++oi){
          float4 w4 = wr[oi][k];
          a[oi][j] += w4.x*p0 + w4.y*p1 + w4.z*p2 + w4.w*p3;
        }
      }
    }
    #pragma unroll
    for (int off = 32; off > 0; off >>= 1){
      #pragma unroll
      for (int oi = 0; oi < 2; ++oi){
        a[oi][0] += __shfl_down(a[oi][0], off, 64);
        a[oi][1] += __shfl_down(a[oi][1], off, 64);
        a[oi][2] += __shfl_down(a[oi][2], off, 64);
      }
    }
    if (lane == 0){
      int n = order[base + s];
      featg[(size_t)n*128 + out0] =
        (lrelu(a[0][0]+b0) + lrelu(a[0][1]+b0) + lrelu(a[0][2]+b0)) * (1.f/3.f);
      featg[(size_t)n*128 + out0 + 1] =
        (lrelu(a[1][0]+b1v) + lrelu(a[1][1]+b1v) + lrelu(a[1][2]+b1v)) * (1.f/3.f);
    }
    __syncthreads();
  }
}

// ---------------- cd tail ----------------
__global__ __launch_bounds__(128) void cd_tail_kernel(
    const float* __restrict__ featg,
    const int*   __restrict__ clsb,
    const float* __restrict__ cstyle,
    const float* __restrict__ W1,
    const float* __restrict__ b1,
    const float* __restrict__ W2,
    const float* __restrict__ b2,
    float* __restrict__ pChar)
{
  __shared__ float feat[160];
  __shared__ float red2[2];
  int n = blockIdx.x, tid = threadIdx.x;
  int b = n >> 7;
  int e = clsb[n];
  int o = tid;
  feat[o] = featg[(size_t)n*128 + o];
  if (tid < 32) feat[128+tid] = cstyle[(b*80 + e)*32 + tid];
  __syncthreads();

  float s = b1[e*128 + o];
  for (int d=0;d<160;d++) s += feat[d]*W1[(e*160 + d)*128 + o];
  float h = s > 0.f ? s : 0.f;
  float contrib = h * W2[e*128 + o];
  #pragma unroll
  for (int off=32; off>0; off>>=1) contrib += __shfl_down(contrib, off, 64);
  if ((tid & 63) == 0) red2[tid>>6] = contrib;
  __syncthreads();
  if (tid == 0) pChar[n] = red2[0] + red2[1] + b2[e];
}

extern "C" void kernel_launch(void* const* d_in, const int* in_sizes, int n_in,
                              void* d_out, int out_size, void* d_ws, size_t ws_size,
                              hipStream_t stream){
  (void)in_sizes; (void)n_in; (void)out_size; (void)ws_size;
  const float* x      = (const float*)d_in[0];
  const float* label  = (const float*)d_in[1];
  const float* g_style= (const float*)d_in[2];
  const float* spaced = (const float*)d_in[3];
  const float* cstyle = (const float*)d_in[4];
  const float* sp1    = (const float*)d_in[5];
  const float* sp2    = (const float*)d_in[6];
  const float* in_w   = (const float*)d_in[7];
  const float* in_b   = (const float*)d_in[8];
  const float* c1w1   = (const float*)d_in[9];
  const float* c1b1   = (const float*)d_in[10];
  const float* c1w2   = (const float*)d_in[11];
  const float* c1b2   = (const float*)d_in[12];
  const float* c2w    = (const float*)d_in[13];
  const float* c2b    = (const float*)d_in[14];
  const float* c3w1   = (const float*)d_in[15];
  const float* c3b1   = (const float*)d_in[16];
  const float* c3w2   = (const float*)d_in[17];
  const float* c3b2   = (const float*)d_in[18];
  const float* fm_w   = (const float*)d_in[19];
  const float* fm_b   = (const float*)d_in[20];
  const float* cdw    = (const float*)d_in[21];
  const float* cdb    = (const float*)d_in[22];
  const float* fc1w   = (const float*)d_in[23];
  const float* fc1b   = (const float*)d_in[24];
  const float* fc2w   = (const float*)d_in[25];
  const float* fc2b   = (const float*)d_in[26];
  float* out = (float*)d_out;
  char* ws = (char*)d_ws;

  ushort* h1b  = (ushort*)(ws + 0);                // 7,602,176
  ushort* A2h  = (ushort*)(ws + 7602176);          // 7,340,032
  ushort* pwgh = (ushort*)(ws + 7602176);          // 3,538,944 (A2h dead by then)
  ushort* P3b  = (ushort*)(ws + 22282240);         // 1,835,008
  ushort* A4b  = (ushort*)(ws + 24117248);         // 3,407,872
  ushort* A5h  = (ushort*)(ws + 27525120);         // 3,145,728
  ushort* P5b  = (ushort*)(ws + 33816576);         // 786,432
  ushort* A6b  = (ushort*)(ws + 34603008);         // 655,360
  ushort* P6b  = (ushort*)(ws + 35258368);         // 163,840
  float*  A7   = (float*) (ws + 35422208);         // 1,572,864
  float*  featg= (float*) (ws + 36995072);         // 131,072
  ushort* Wb2  = (ushort*)(ws + 37126144);         // 73,728
  ushort* Wb4  = (ushort*)(ws + 37199872);         // 147,456
  ushort* Wb5  = (ushort*)(ws + 37347328);         // 294,912
  ushort* Wb6  = (ushort*)(ws + 37642240);         // 294,912
  ushort* Wb7  = (ushort*)(ws + 37937152);         // 589,824
  float*  map6 = (float*) (ws + 38526976);         // 131,072
  float*  map1 = (float*) (ws + 38658048);         // 1,536
  float*  map2 = (float*) (ws + 38659584);         // 3,072
  int*    clsb = (int*)   (ws + 38663424);         // 1,024
  int*    order= (int*)   (ws + 38664448);         // 1,024
  int*    cntv = (int*)   (ws + 38665472);         // 320
  int*    offv = (int*)   (ws + 38665792);         // 320

  setup_kernel<<<2,256,0,stream>>>(g_style, sp1, sp2, c1w1, c1b1, c2w, c2b, label,
                                   map1, map2, clsb, cntv, offv, order);
  repack_all<<<2736,256,0,stream>>>(c1w1, c1w2, c2w, c3w1, c3w2, Wb2, Wb4, Wb5, Wb6, Wb7);
  map6_kernel<<<128,256,0,stream>>>(spaced, label, c3w1, c3b1, map6);

  // h1 (bf16)
  conv_in_kernel<<<dim3(116,8,2),256,0,stream>>>(x, in_w, in_b, h1b);
  // A2 = lrelu(conv(h1) + map1) : MFMA, bf16 out
  conv_mfma<64,512,58,64,1,1><<<dim3(448,1,2),256,0,stream>>>(h1b, Wb2, map1, nullptr, A2h);
  // P3 (bf16 -> bf16)
  pool2_h2h_kernel<<<3584,256,0,stream>>>(A2h, P3b, 56, 512, 917504);
  // A4 = lrelu(conv(P3) + b) : MFMA, bf16 out
  conv_mfma<64,256,28,128,0,1><<<dim3(104,2,2),256,0,stream>>>(P3b, Wb4, c1b2, nullptr, A4b);
  // A5 = lrelu(conv(A4) + map2) : MFMA, bf16 out
  conv_mfma<128,256,26,128,1,1><<<dim3(96,2,2),256,0,stream>>>(A4b, Wb5, map2, nullptr, A5h);
  // P5 (bf16 -> bf16)
  pool2_h2h_kernel<<<1536,256,0,stream>>>(A5h, P5b, 24, 256, 393216);
  // A6 = lrelu(conv(P5) + map6) : MFMA MODE2, bf16 out
  conv_mfma<128,128,12,128,2,1><<<dim3(20,2,2),256,0,stream>>>(P5b, Wb6, map6, nullptr, A6b);
  // P6 (bf16 -> bf16)
  pool2_h2h_kernel<<<320,256,0,stream>>>(A6b, P6b, 10, 128, 81920);
  // A7 = lrelu(conv(P6) + b) : MFMA, f32 out
  conv_mfma<128,64,5,256,0,0><<<dim3(3,4,2),256,0,stream>>>(P6b, Wb7, c3b2, A7, nullptr);
  // pM
  fm_kernel<<<128,256,0,stream>>>(A7, fm_w, fm_b, out);
  // pChar: im2col(bf16) -> grouped conv (LDS dbuf) -> tail
  im2col_kernel<<<6912,256,0,stream>>>(A7, pwgh);
  cd_conv_kernel<<<dim3(80,16),256,0,stream>>>(pwgh, cntv, offv, order, cdw, cdb, featg);
  cd_tail_kernel<<<256,128,0,stream>>>(featg, clsb, cstyle, fc1w, fc1b, fc2w, fc2b, out + 128);
}

// Round 13
// 312.319 us; speedup vs baseline: 1.0669x; 1.0555x over previous
//
#include <hip/hip_runtime.h>
#include <hip/hip_bf16.h>

#define LEAKC 0.1f

__device__ __forceinline__ float lrelu(float v){ return v > 0.f ? v : LEAKC*v; }
__device__ __forceinline__ ushort f2b(float f){
  __hip_bfloat16 h = __float2bfloat16(f);
  return *reinterpret_cast<ushort*>(&h);
}
__device__ __forceinline__ float b2f(ushort u){
  __hip_bfloat16 h = *reinterpret_cast<__hip_bfloat16*>(&u);
  return __bfloat162float(h);
}

typedef __attribute__((ext_vector_type(8))) short bf16x8;
typedef __attribute__((ext_vector_type(4))) float f32x4;

// ---------------- setup: block0 = styles + map1 + map2; block1 = cls counting sort ----------------
__global__ __launch_bounds__(256) void setup_kernel(
    const float* __restrict__ g, const float* __restrict__ sp1, const float* __restrict__ sp2,
    const float* __restrict__ c1w1, const float* __restrict__ c1b1,
    const float* __restrict__ c2w,  const float* __restrict__ c2b,
    const float* __restrict__ label,
    float* __restrict__ map1, float* __restrict__ map2,
    int* __restrict__ clsb, int* __restrict__ cnt, int* __restrict__ off, int* __restrict__ order){
  int t = threadIdx.x;
  if (blockIdx.x == 0){
    __shared__ float s1s[64], s2s[128];
    if (t < 64){
      int b = t >> 5, j = t & 31;
      float a = 0.f;
      for (int k=0;k<256;k++) a += g[b*256+k]*sp1[j*256+k];
      s1s[t] = a;
    } else if (t < 192){
      int u = t - 64;
      int b = u >> 6, j = u & 63;
      float a = 0.f;
      for (int k=0;k<256;k++) a += g[b*256+k]*sp2[j*256+k];
      s2s[u] = a;
    }
    __syncthreads();
    if (t < 128){           // map1
      int b = t >> 6, o = t & 63;
      float S0=0.f,S1=0.f,S2=0.f;
      for (int c=0;c<32;c++){
        float s = s1s[b*32+c];
        const float* wq = c1w1 + ((size_t)o*96 + 64 + c)*9;
        S0 += s*(wq[0]+wq[3]+wq[6]);
        S1 += s*(wq[1]+wq[4]+wq[7]);
        S2 += s*(wq[2]+wq[5]+wq[8]);
      }
      float bb = c1b1[o];
      map1[t*3+0]=S1+S2+bb; map1[t*3+1]=S0+S1+S2+bb; map1[t*3+2]=S0+S1+bb;
    }
    {                        // map2
      int b = t >> 7, o = t & 127;
      float S0=0.f,S1=0.f,S2=0.f;
      for (int c=0;c<64;c++){
        float s = s2s[b*64+c];
        const float* wq = c2w + ((size_t)o*192 + 128 + c)*9;
        S0 += s*(wq[0]+wq[3]+wq[6]);
        S1 += s*(wq[1]+wq[4]+wq[7]);
        S2 += s*(wq[2]+wq[5]+wq[8]);
      }
      float bb = c2b[o];
      map2[t*3+0]=S1+S2+bb; map2[t*3+1]=S0+S1+S2+bb; map2[t*3+2]=S0+S1+bb;
    }
  } else {
    __shared__ int h[80], hoff[80];
    if (t < 80) h[t] = 0;
    __syncthreads();
    int b = t >> 7, tt = t & 127;
    const float* p = label + (tt*2 + b)*80;
    float best = p[0]; int bi = 0;
    for (int c=1;c<80;c++){ float v = p[c]; if (v > best){ best = v; bi = c; } }
    clsb[t] = bi;
    atomicAdd(&h[bi], 1);
    __syncthreads();
    if (t == 0){
      int s = 0;
      for (int e=0;e<80;e++){ hoff[e] = s; s += h[e]; }
    }
    __syncthreads();
    if (t < 80){ cnt[t] = h[t]; off[t] = hoff[t]; }
    __syncthreads();
    int rank = atomicAdd(&hoff[bi], 1);
    order[rank] = t;
  }
}

// ---------------- one repack kernel for all 5 weight tensors ----------------
__device__ __forceinline__ void pack1(int idx, const float* __restrict__ w,
                                      ushort* __restrict__ wb, int CM, int CTOT){
  int c = idx % CM; int r = idx / CM; int t = r % 9; int n = r / 9;
  wb[idx] = f2b(w[((size_t)n*CTOT + c)*9 + t]);
}
__global__ void repack_all(const float* __restrict__ c1w1, const float* __restrict__ c1w2,
                           const float* __restrict__ c2w,  const float* __restrict__ c3w1,
                           const float* __restrict__ c3w2,
                           ushort* __restrict__ Wb2, ushort* __restrict__ Wb4,
                           ushort* __restrict__ Wb5, ushort* __restrict__ Wb6,
                           ushort* __restrict__ Wb7){
  int i = blockIdx.x*256 + threadIdx.x;
  if      (i < 36864)  pack1(i,        c1w1, Wb2, 64, 96);
  else if (i < 110592) pack1(i-36864,  c1w2, Wb4, 64, 64);
  else if (i < 258048) pack1(i-110592, c2w,  Wb5, 128, 192);
  else if (i < 405504) pack1(i-258048, c3w1, Wb6, 128, 240);
  else if (i < 700416) pack1(i-405504, c3w2, Wb7, 128, 128);
}

// ---------------- input conv 7x7 -> bf16 out ----------------
__global__ void conv_in_kernel(const float* __restrict__ x,
                               const float* __restrict__ wgt,
                               const float* __restrict__ bias,
                               ushort* __restrict__ out){
  int hw = blockIdx.x*256 + threadIdx.x;
  int y = hw >> 9, w = hw & 511;
  int b = blockIdx.z;
  int o0 = blockIdx.y * 8;
  float acc[8];
  #pragma unroll
  for (int i=0;i<8;i++) acc[i] = bias[o0+i];
  for (int kh=0;kh<7;kh++){
    const float* ip = x + (b*64 + y + kh)*512;
    #pragma unroll
    for (int kw=0;kw<7;kw++){
      int wi = w + kw - 3;
      float v = (wi>=0 && wi<512) ? ip[wi] : 0.f;
      #pragma unroll
      for (int i=0;i<8;i++) acc[i] += v * wgt[(o0+i)*49 + kh*7 + kw];
    }
  }
  #pragma unroll
  for (int i=0;i<8;i++)
    out[((b*64 + o0+i)*58 + y)*512 + w] = f2b(lrelu(acc[i]));
}

// ---------------- MFMA conv: 3x3, pad(0,1), BM=64, BN=64, K=CM*9 ----------------
template<int CM,int WID,int HIN,int COUT,int MODE,int OUTBF>
__global__ __launch_bounds__(256) void conv_mfma(
    const ushort* __restrict__ in,
    const ushort* __restrict__ Wb,
    const float*  __restrict__ mb,
    float* __restrict__ outf,
    ushort* __restrict__ outh){
  constexpr int HOUT = HIN - 2;
  constexpr int KTOT = CM*9;
  constexpr int SLABS = CM/32;
  constexpr int NST = 3*SLABS;
  __shared__ ushort A[2][66][40];
  int tid = threadIdx.x, lane = tid & 63, wave = tid >> 6;
  int mt = blockIdx.x;
  int y  = mt / (WID/64), w0 = (mt % (WID/64))*64;
  int n0 = blockIdx.y*64;
  int b  = blockIdx.z;

  f32x4 acc[4];
  #pragma unroll
  for (int nf=0;nf<4;nf++) acc[nf] = (f32x4){0.f,0.f,0.f,0.f};

  auto stage = [&](int s, int bufi){
    int kh = s / SLABS;
    int c0 = (s % SLABS)*32;
    const ushort* base = in + ((size_t)(b*CM + c0)*HIN + (y+kh))*WID;
    int c2 = (tid & 15)*2, m0v = (tid >> 4)*2*2;
    const ushort* p0 = base + (size_t)c2*HIN*WID + w0 + m0v;
    const ushort* p1 = p0 + (size_t)HIN*WID;
    ushort4 va = *(const ushort4*)p0;
    ushort4 vb = *(const ushort4*)p1;
    uint* dst = (uint*)&A[bufi][1+m0v][c2];
    dst[0]  = (uint)va.x | ((uint)vb.x << 16);
    dst[20] = (uint)va.y | ((uint)vb.y << 16);
    dst[40] = (uint)va.z | ((uint)vb.z << 16);
    dst[60] = (uint)va.w | ((uint)vb.w << 16);
    if (tid < 64){
      int c = tid & 31, side = tid >> 5;
      int w = side ? (w0 + 64) : (w0 - 1);
      ushort v = 0;
      if (w >= 0 && w < WID) v = base[(size_t)c*HIN*WID + w];
      A[bufi][side ? 65 : 0][c] = v;
    }
  };

  stage(0, 0);
  __syncthreads();
  for (int s = 0; s < NST; ++s){
    int cur = s & 1;
    if (s + 1 < NST) stage(s+1, cur ^ 1);
    int kh = s / SLABS;
    int c0 = (s % SLABS)*32;
    #pragma unroll
    for (int kw = 0; kw < 3; ++kw){
      bf16x8 a = *(bf16x8*)&A[cur][wave*16 + (lane & 15) + kw][(lane >> 4)*8];
      #pragma unroll
      for (int nf = 0; nf < 4; ++nf){
        const ushort* wp = Wb + (size_t)(n0 + nf*16 + (lane & 15))*KTOT
                              + (kh*3 + kw)*CM + c0 + (lane >> 4)*8;
        bf16x8 bb = *(const bf16x8*)wp;
        acc[nf] = __builtin_amdgcn_mfma_f32_16x16x32_bf16(a, bb, acc[nf], 0, 0, 0);
      }
    }
    __syncthreads();
  }

  int mrow = wave*16 + ((lane >> 4) << 2);
  int w = w0 + mrow;
  #pragma unroll
  for (int nf = 0; nf < 4; ++nf){
    int n = n0 + nf*16 + (lane & 15);
    float r0 = acc[nf][0], r1 = acc[nf][1], r2 = acc[nf][2], r3 = acc[nf][3];
    if (MODE == 0){
      float bb = mb[n];
      r0 += bb; r1 += bb; r2 += bb; r3 += bb;
    } else if (MODE == 1){
      const float* m3 = mb + (size_t)(b*COUT + n)*3;
      float mL = m3[0], mM = m3[1], mR = m3[2];
      r0 += (w == 0) ? mL : ((w   == WID-1) ? mR : mM);
      r1 += (w+1 == WID-1) ? mR : mM;
      r2 += (w+2 == WID-1) ? mR : mM;
      r3 += (w+3 == WID-1) ? mR : mM;
    } else {
      const float* m6 = mb + ((size_t)(b*COUT + n))*WID + w;
      r0 += m6[0]; r1 += m6[1]; r2 += m6[2]; r3 += m6[3];
    }
    r0 = lrelu(r0); r1 = lrelu(r1); r2 = lrelu(r2); r3 = lrelu(r3);
    size_t off = ((size_t)(b*COUT + n)*HOUT + y)*WID + w;
    if (OUTBF){
      ushort4 o = make_ushort4(f2b(r0), f2b(r1), f2b(r2), f2b(r3));
      *(ushort4*)(outh + off) = o;
    } else {
      *(float4*)(outf + off) = make_float4(r0, r1, r2, r3);
    }
  }
}

// ---------------- A6 column map (includes bias) ----------------
__global__ void map6_kernel(const float* __restrict__ spaced,
                            const float* __restrict__ label,
                            const float* __restrict__ wgt,
                            const float* __restrict__ bias,
                            float* __restrict__ mapv){
  int n = blockIdx.x*256 + threadIdx.x;
  int w = n & 127, o = (n >> 7) & 127, b = n >> 14;
  float a = bias[o];
  #pragma unroll
  for (int t=0;t<3;t++){
    int j = w + t - 1;
    if (j < 0 || j >= 128) continue;
    const float* sp = spaced + (j*2 + b)*32;
    const float* lb = label + (j*2 + b)*80;
    for (int c=0;c<32;c++){
      const float* wq = wgt + ((size_t)o*240 + 128 + c)*9 + t;
      a += sp[c]*(wq[0]+wq[3]+wq[6]);
    }
    for (int c=0;c<80;c++){
      const float* wq = wgt + ((size_t)o*240 + 160 + c)*9 + t;
      a += lb[c]*(wq[0]+wq[3]+wq[6]);
    }
  }
  mapv[n] = a;
}

// ---------------- 2x2 mean pool (bf16 -> bf16) ----------------
__global__ void pool2_h2h_kernel(const ushort* __restrict__ in, ushort* __restrict__ out,
                                 int H, int W, int total){
  int n = blockIdx.x*256 + threadIdx.x;
  if (n >= total) return;
  int Wo = W >> 1;
  int wo = n % Wo;
  int r = n / Wo;
  int Ho = H >> 1;
  int ho = r % Ho;
  int bc = r / Ho;
  const ushort* p = in + (bc*H + 2*ho)*W + 2*wo;
  out[n] = f2b(0.25f*(b2f(p[0]) + b2f(p[1]) + b2f(p[W]) + b2f(p[W+1])));
}

// ---------------- pM ----------------
__global__ __launch_bounds__(256) void fm_kernel(const float* __restrict__ A7,
                          const float* __restrict__ fw,
                          const float* __restrict__ fb,
                          float* __restrict__ out){
  __shared__ float red[4];
  int n = blockIdx.x;
  int b = n >> 6, w = n & 63;
  int c = threadIdx.x;
  float a = 0.f;
  #pragma unroll
  for (int r=0;r<3;r++){
    const float* ip = A7 + ((b*256+c)*3+r)*64;
    const float* wp = fw + (c*3+r)*3;
    #pragma unroll
    for (int kw=0;kw<3;kw++){
      int wi = w + kw - 1;
      if (wi>=0 && wi<64) a += ip[wi]*wp[kw];
    }
  }
  #pragma unroll
  for (int off=32; off>0; off>>=1) a += __shfl_down(a, off, 64);
  if ((threadIdx.x & 63) == 0) red[threadIdx.x>>6] = a;
  __syncthreads();
  if (threadIdx.x == 0) out[n] = red[0]+red[1]+red[2]+red[3] + fb[0];
}

// ---------------- im2col -> bf16: pwgh[n][j][d] (d = c*9 + r*3 + kw) ----------------
__global__ void im2col_kernel(const float* __restrict__ A7, ushort* __restrict__ pwgh){
  int i = blockIdx.x*256 + threadIdx.x;
  if (i >= 256*3*2304) return;
  int d = i % 2304; int rj = i / 2304; int j = rj % 3; int n = rj / 3;
  int b = n >> 7, t = n & 127; int idx = t >> 1;
  int c = d / 9, rem = d - c*9, r = rem / 3, kw = rem - r*3;
  int col = idx - 2 + kw + j;
  pwgh[i] = (col >= 0 && col < 64) ? f2b(A7[((size_t)(b*256 + c)*3 + r)*64 + col]) : (ushort)0;
}

// ---------------- cd conv v6: grouped-GEMM MFMA, uniform work, weights once ----------------
// grid (80, 8): block = (class e, 16 outputs). M = up-to-48 patch rows (samples x 3 windows),
// K = 2304 split across 4 waves (576 each), LDS cross-wave reduce. Weights f32->bf16 on the fly.
__global__ __launch_bounds__(256) void cd_conv_kernel(
    const ushort* __restrict__ pwgh,  // (256,3,2304) bf16
    const int*   __restrict__ cnt,    // (80)
    const int*   __restrict__ offv,   // (80)
    const int*   __restrict__ order,  // (256)
    const float* __restrict__ Wc,     // (80,128,2304) f32
    float* __restrict__ comat)        // (256,128,3) raw conv outputs
{
  __shared__ int rowOff[48];
  __shared__ f32x4 red[4][3][64];     // 12,288 B
  int e = blockIdx.x, og = blockIdx.y;
  int m = cnt[e];
  if (m == 0) return;
  int base = offv[e];
  int tid = threadIdx.x, lane = tid & 63, wave = tid >> 6;

  const float* wb_base = Wc + ((size_t)(e*128) + og*16 + (lane & 15))*2304;
  int kbase = wave*576 + ((lane >> 4)*8);

  for (int s0 = 0; s0 < m; s0 += 16){
    int rowsChunk = 3*(m - s0); if (rowsChunk > 48) rowsChunk = 48;
    if (tid < 48){
      int lr = s0 + tid/3;
      rowOff[tid] = (lr < m) ? (order[base+lr]*3 + (tid - (tid/3)*3))*2304 : -1;
    }
    __syncthreads();

    int offA[3];
    #pragma unroll
    for (int mt=0; mt<3; mt++) offA[mt] = rowOff[mt*16 + (lane & 15)];

    f32x4 acc[3];
    #pragma unroll
    for (int mt=0; mt<3; mt++) acc[mt] = (f32x4){0.f,0.f,0.f,0.f};

    for (int kk = 0; kk < 18; ++kk){
      int k0 = kbase + kk*32;
      const float* wb = wb_base + k0;
      float4 wv0 = *(const float4*)wb;
      float4 wv1 = *(const float4*)(wb + 4);
      bf16x8 bfr = { (short)f2b(wv0.x), (short)f2b(wv0.y), (short)f2b(wv0.z), (short)f2b(wv0.w),
                     (short)f2b(wv1.x), (short)f2b(wv1.y), (short)f2b(wv1.z), (short)f2b(wv1.w) };
      #pragma unroll
      for (int mt=0; mt<3; mt++){
        if (mt*16 < rowsChunk){          // block-uniform guard
          bf16x8 af = {0,0,0,0,0,0,0,0};
          if (offA[mt] >= 0) af = *(const bf16x8*)&pwgh[offA[mt] + k0];
          acc[mt] = __builtin_amdgcn_mfma_f32_16x16x32_bf16(af, bfr, acc[mt], 0, 0, 0);
        }
      }
    }

    #pragma unroll
    for (int mt=0; mt<3; mt++) red[wave][mt][lane] = acc[mt];
    __syncthreads();

    if (wave < 3){
      int mt = wave;
      if (mt*16 < rowsChunk){
        f32x4 s4 = red[0][mt][lane];
        #pragma unroll
        for (int w2=1; w2<4; w2++){
          f32x4 t4 = red[w2][mt][lane];
          s4[0]+=t4[0]; s4[1]+=t4[1]; s4[2]+=t4[2]; s4[3]+=t4[3];
        }
        int col = og*16 + (lane & 15);
        #pragma unroll
        for (int r=0; r<4; r++){
          int row = mt*16 + ((lane >> 4) << 2) + r;
          if (row < rowsChunk){
            int lrank = s0 + row/3, j = row - (row/3)*3;
            int n = order[base + lrank];
            comat[((size_t)n*128 + col)*3 + j] = s4[r];
          }
        }
      }
    }
    __syncthreads();
  }
}

// ---------------- cd tail: comat -> pooled feat -> fc1 -> fc2 ----------------
__global__ __launch_bounds__(128) void cd_tail_kernel(
    const float* __restrict__ comat,  // (256,128,3)
    const int*   __restrict__ clsb,
    const float* __restrict__ bcv,    // (80,128)
    const float* __restrict__ cstyle,
    const float* __restrict__ W1,
    const float* __restrict__ b1,
    const float* __restrict__ W2,
    const float* __restrict__ b2,
    float* __restrict__ pChar)
{
  __shared__ float feat[160];
  __shared__ float red2[2];
  int n = blockIdx.x, tid = threadIdx.x;
  int b = n >> 7;
  int e = clsb[n];
  int o = tid;
  const float* cm = comat + ((size_t)n*128 + o)*3;
  float bb = bcv[e*128 + o];
  feat[o] = (lrelu(cm[0]+bb) + lrelu(cm[1]+bb) + lrelu(cm[2]+bb)) * (1.f/3.f);
  if (tid < 32) feat[128+tid] = cstyle[(b*80 + e)*32 + tid];
  __syncthreads();

  float s = b1[e*128 + o];
  for (int d=0;d<160;d++) s += feat[d]*W1[(e*160 + d)*128 + o];
  float h = s > 0.f ? s : 0.f;
  float contrib = h * W2[e*128 + o];
  #pragma unroll
  for (int off=32; off>0; off>>=1) contrib += __shfl_down(contrib, off, 64);
  if ((tid & 63) == 0) red2[tid>>6] = contrib;
  __syncthreads();
  if (tid == 0) pChar[n] = red2[0] + red2[1] + b2[e];
}

extern "C" void kernel_launch(void* const* d_in, const int* in_sizes, int n_in,
                              void* d_out, int out_size, void* d_ws, size_t ws_size,
                              hipStream_t stream){
  (void)in_sizes; (void)n_in; (void)out_size; (void)ws_size;
  const float* x      = (const float*)d_in[0];
  const float* label  = (const float*)d_in[1];
  const float* g_style= (const float*)d_in[2];
  const float* spaced = (const float*)d_in[3];
  const float* cstyle = (const float*)d_in[4];
  const float* sp1    = (const float*)d_in[5];
  const float* sp2    = (const float*)d_in[6];
  const float* in_w   = (const float*)d_in[7];
  const float* in_b   = (const float*)d_in[8];
  const float* c1w1   = (const float*)d_in[9];
  const float* c1b1   = (const float*)d_in[10];
  const float* c1w2   = (const float*)d_in[11];
  const float* c1b2   = (const float*)d_in[12];
  const float* c2w    = (const float*)d_in[13];
  const float* c2b    = (const float*)d_in[14];
  const float* c3w1   = (const float*)d_in[15];
  const float* c3b1   = (const float*)d_in[16];
  const float* c3w2   = (const float*)d_in[17];
  const float* c3b2   = (const float*)d_in[18];
  const float* fm_w   = (const float*)d_in[19];
  const float* fm_b   = (const float*)d_in[20];
  const float* cdw    = (const float*)d_in[21];
  const float* cdb    = (const float*)d_in[22];
  const float* fc1w   = (const float*)d_in[23];
  const float* fc1b   = (const float*)d_in[24];
  const float* fc2w   = (const float*)d_in[25];
  const float* fc2b   = (const float*)d_in[26];
  float* out = (float*)d_out;
  char* ws = (char*)d_ws;

  ushort* h1b  = (ushort*)(ws + 0);                // 7,602,176
  ushort* A2h  = (ushort*)(ws + 7602176);          // 7,340,032
  ushort* pwgh = (ushort*)(ws + 7602176);          // 3,538,944 (A2h dead by then)
  ushort* P3b  = (ushort*)(ws + 22282240);         // 1,835,008
  ushort* A4b  = (ushort*)(ws + 24117248);         // 3,407,872
  ushort* A5h  = (ushort*)(ws + 27525120);         // 3,145,728
  ushort* P5b  = (ushort*)(ws + 33816576);         // 786,432
  ushort* A6b  = (ushort*)(ws + 34603008);         // 655,360
  ushort* P6b  = (ushort*)(ws + 35258368);         // 163,840
  float*  A7   = (float*) (ws + 35422208);         // 1,572,864
  float*  comat= (float*) (ws + 36995072);         // 393,216
  ushort* Wb2  = (ushort*)(ws + 37388288);         // 73,728
  ushort* Wb4  = (ushort*)(ws + 37462016);         // 147,456
  ushort* Wb5  = (ushort*)(ws + 37609472);         // 294,912
  ushort* Wb6  = (ushort*)(ws + 37904384);         // 294,912
  ushort* Wb7  = (ushort*)(ws + 38199296);         // 589,824
  float*  map6 = (float*) (ws + 38789120);         // 131,072
  float*  map1 = (float*) (ws + 38920192);         // 1,536
  float*  map2 = (float*) (ws + 38921728);         // 3,072
  int*    clsb = (int*)   (ws + 38924800);         // 1,024
  int*    order= (int*)   (ws + 38925824);         // 1,024
  int*    cntv = (int*)   (ws + 38926848);         // 320
  int*    offv = (int*)   (ws + 38927168);         // 320

  setup_kernel<<<2,256,0,stream>>>(g_style, sp1, sp2, c1w1, c1b1, c2w, c2b, label,
                                   map1, map2, clsb, cntv, offv, order);
  repack_all<<<2736,256,0,stream>>>(c1w1, c1w2, c2w, c3w1, c3w2, Wb2, Wb4, Wb5, Wb6, Wb7);
  map6_kernel<<<128,256,0,stream>>>(spaced, label, c3w1, c3b1, map6);

  // h1 (bf16)
  conv_in_kernel<<<dim3(116,8,2),256,0,stream>>>(x, in_w, in_b, h1b);
  // A2 = lrelu(conv(h1) + map1) : MFMA, bf16 out
  conv_mfma<64,512,58,64,1,1><<<dim3(448,1,2),256,0,stream>>>(h1b, Wb2, map1, nullptr, A2h);
  // P3 (bf16 -> bf16)
  pool2_h2h_kernel<<<3584,256,0,stream>>>(A2h, P3b, 56, 512, 917504);
  // A4 = lrelu(conv(P3) + b) : MFMA, bf16 out
  conv_mfma<64,256,28,128,0,1><<<dim3(104,2,2),256,0,stream>>>(P3b, Wb4, c1b2, nullptr, A4b);
  // A5 = lrelu(conv(A4) + map2) : MFMA, bf16 out
  conv_mfma<128,256,26,128,1,1><<<dim3(96,2,2),256,0,stream>>>(A4b, Wb5, map2, nullptr, A5h);
  // P5 (bf16 -> bf16)
  pool2_h2h_kernel<<<1536,256,0,stream>>>(A5h, P5b, 24, 256, 393216);
  // A6 = lrelu(conv(P5) + map6) : MFMA MODE2, bf16 out
  conv_mfma<128,128,12,128,2,1><<<dim3(20,2,2),256,0,stream>>>(P5b, Wb6, map6, nullptr, A6b);
  // P6 (bf16 -> bf16)
  pool2_h2h_kernel<<<320,256,0,stream>>>(A6b, P6b, 10, 128, 81920);
  // A7 = lrelu(conv(P6) + b) : MFMA, f32 out
  conv_mfma<128,64,5,256,0,0><<<dim3(3,4,2),256,0,stream>>>(P6b, Wb7, c3b2, A7, nullptr);
  // pM
  fm_kernel<<<128,256,0,stream>>>(A7, fm_w, fm_b, out);
  // pChar: im2col(bf16) -> grouped-GEMM conv -> tail
  im2col_kernel<<<6912,256,0,stream>>>(A7, pwgh);
  cd_conv_kernel<<<dim3(80,8),256,0,stream>>>(pwgh, cntv, offv, order, cdw, comat);
  cd_tail_kernel<<<256,128,0,stream>>>(comat, clsb, cdb, cstyle, fc1w, fc1b, fc2w, fc2b, out + 128);
}